// Round 1
// 926.714 us; speedup vs baseline: 1.1021x; 1.1021x over previous
//
#include <hip/hip_runtime.h>

// HSN layer: out = sigmoid( A0 @ (sig(A0 @ (x W1_00)) W2_00) + B1 @ (sig(B1^T @ (x W1_01)) W2_10) )
// C = 128 fixed. CSR-gather SpMM (no f32 atomics) + MFMA GEMMs.
// Intermediate features in bf16 (256 B/row) to halve gather traffic.
// CSR build: two-level LDS counting sort (bucket_count/scan/bucket_scatter/
// bucket_to_csr) -- replaces global-atomic hist + random 8B scatter whose
// write-allocate traffic (198 MB/launch at 12% HBM util) dominated profiles.

#define CF 128
#define RB 64          // rows per bucket (2^RB_SHIFT)
#define RB_SHIFT 6
#define NPASSBLK 128   // blocks (chunks) in count/scatter passes

typedef __attribute__((ext_vector_type(8))) short bf16x8;
typedef __attribute__((ext_vector_type(4))) float f32x4;

// f32 -> bf16 round-to-nearest-even (finite inputs)
__device__ __forceinline__ unsigned short bf16rne(float f) {
  unsigned u = __float_as_uint(f);
  u += 0x7FFFu + ((u >> 16) & 1u);
  return (unsigned short)(u >> 16);
}
// packed pair of bf16 (low short = even feature) -> two floats
__device__ __forceinline__ float2 bf2f(unsigned u) {
  return make_float2(__uint_as_float(u << 16), __uint_as_float(u & 0xFFFF0000u));
}
// split f32 -> bf16 hi (trunc) + bf16 lo (residual)
__device__ __forceinline__ void splitf(float f, short& h, short& l) {
  unsigned u = __float_as_uint(f);
  h = (short)(u >> 16);
  float fh = __uint_as_float(u & 0xFFFF0000u);
  float r = f - fh;
  l = (short)(__float_as_uint(r) >> 16);
}

// ---------------------------------------------------------------------------
// Pack W[128][128] f32 (row-major [k][n]) into mfma_f32_16x16x32_bf16
// B-fragment order: frag[(s*8+t)*64+lane][j] = W[s*32+(lane>>4)*8+j][t*16+(lane&15)]
// ---------------------------------------------------------------------------
__global__ __launch_bounds__(256)
void pack_w(const float* __restrict__ W, short* __restrict__ hi,
            short* __restrict__ lo) {
  const int tid = blockIdx.x * 256 + threadIdx.x;   // 0..2047
  if (tid >= 2048) return;
  const int lane = tid & 63;
  const int t = (tid >> 6) & 7;
  const int s = tid >> 9;
  const int n = t * 16 + (lane & 15);
  const int k0 = s * 32 + ((lane >> 4) << 3);
  short* hp = hi + (size_t)tid * 8;
  short* lp = lo + (size_t)tid * 8;
#pragma unroll
  for (int j = 0; j < 8; ++j) {
    short h, l;
    splitf(W[(size_t)(k0 + j) * CF + n], h, l);
    hp[j] = h;
    lp[j] = l;
  }
}

// ---------------------------------------------------------------------------
// GEMM (f32 in, bf16 out): Y = X @ W, 3-term hi/lo split MFMA.
// ---------------------------------------------------------------------------
__global__ __launch_bounds__(128)
void gemm_f32_b16(const float* __restrict__ X, const short* __restrict__ Whi,
                  const short* __restrict__ Wlo, unsigned short* __restrict__ Y,
                  int M) {
  const int wave = threadIdx.x >> 6;
  const int lane = threadIdx.x & 63;
  const int mrow = lane & 15;
  const int quad = lane >> 4;
  const int row0 = blockIdx.x * 64 + wave * 32;

  const bf16x8* WH = (const bf16x8*)Whi;
  const bf16x8* WL = (const bf16x8*)Wlo;

  f32x4 acc[2][8];
#pragma unroll
  for (int mt = 0; mt < 2; ++mt)
#pragma unroll
    for (int t = 0; t < 8; ++t) acc[mt][t] = (f32x4){0.f, 0.f, 0.f, 0.f};

  int rA0 = row0 + mrow;      if (rA0 > M - 1) rA0 = M - 1;
  int rA1 = row0 + 16 + mrow; if (rA1 > M - 1) rA1 = M - 1;
  const float* xp0 = X + (size_t)rA0 * CF + quad * 8;
  const float* xp1 = X + (size_t)rA1 * CF + quad * 8;

#pragma unroll
  for (int s = 0; s < 4; ++s) {
    bf16x8 Ah[2], Al[2];
    const float* p = xp0 + s * 32;
#pragma unroll
    for (int j = 0; j < 8; ++j) { short h, l; splitf(p[j], h, l); Ah[0][j] = h; Al[0][j] = l; }
    p = xp1 + s * 32;
#pragma unroll
    for (int j = 0; j < 8; ++j) { short h, l; splitf(p[j], h, l); Ah[1][j] = h; Al[1][j] = l; }
#pragma unroll
    for (int t = 0; t < 8; ++t) {
      const bf16x8 bh = WH[(s * 8 + t) * 64 + lane];
      const bf16x8 bl = WL[(s * 8 + t) * 64 + lane];
#pragma unroll
      for (int mt = 0; mt < 2; ++mt) {
        acc[mt][t] = __builtin_amdgcn_mfma_f32_16x16x32_bf16(Ah[mt], bh, acc[mt][t], 0, 0, 0);
        acc[mt][t] = __builtin_amdgcn_mfma_f32_16x16x32_bf16(Al[mt], bh, acc[mt][t], 0, 0, 0);
        acc[mt][t] = __builtin_amdgcn_mfma_f32_16x16x32_bf16(Ah[mt], bl, acc[mt][t], 0, 0, 0);
      }
    }
  }

#pragma unroll
  for (int mt = 0; mt < 2; ++mt)
#pragma unroll
    for (int reg = 0; reg < 4; ++reg) {
      const int r = row0 + mt * 16 + quad * 4 + reg;
      if (r < M) {
        unsigned short* yp = Y + (size_t)r * CF + mrow;
#pragma unroll
        for (int t = 0; t < 8; ++t) yp[t * 16] = bf16rne(acc[mt][t][reg]);
      }
    }
}

// ---------------------------------------------------------------------------
// GEMM (bf16 in, bf16 out): Y = X @ W, 2-term (W split) MFMA. In-place safe.
// ---------------------------------------------------------------------------
__global__ __launch_bounds__(128)
void gemm_b16_b16(const unsigned short* __restrict__ X,
                  const short* __restrict__ Whi, const short* __restrict__ Wlo,
                  unsigned short* __restrict__ Y, int M) {
  const int wave = threadIdx.x >> 6;
  const int lane = threadIdx.x & 63;
  const int mrow = lane & 15;
  const int quad = lane >> 4;
  const int row0 = blockIdx.x * 64 + wave * 32;

  const bf16x8* WH = (const bf16x8*)Whi;
  const bf16x8* WL = (const bf16x8*)Wlo;

  f32x4 acc[2][8];
#pragma unroll
  for (int mt = 0; mt < 2; ++mt)
#pragma unroll
    for (int t = 0; t < 8; ++t) acc[mt][t] = (f32x4){0.f, 0.f, 0.f, 0.f};

  int rA0 = row0 + mrow;      if (rA0 > M - 1) rA0 = M - 1;
  int rA1 = row0 + 16 + mrow; if (rA1 > M - 1) rA1 = M - 1;
  const bf16x8* xp0 = (const bf16x8*)(X + (size_t)rA0 * CF + quad * 8);
  const bf16x8* xp1 = (const bf16x8*)(X + (size_t)rA1 * CF + quad * 8);

#pragma unroll
  for (int s = 0; s < 4; ++s) {
    bf16x8 A0 = xp0[s * 4];
    bf16x8 A1 = xp1[s * 4];
#pragma unroll
    for (int t = 0; t < 8; ++t) {
      const bf16x8 bh = WH[(s * 8 + t) * 64 + lane];
      const bf16x8 bl = WL[(s * 8 + t) * 64 + lane];
      acc[0][t] = __builtin_amdgcn_mfma_f32_16x16x32_bf16(A0, bh, acc[0][t], 0, 0, 0);
      acc[0][t] = __builtin_amdgcn_mfma_f32_16x16x32_bf16(A0, bl, acc[0][t], 0, 0, 0);
      acc[1][t] = __builtin_amdgcn_mfma_f32_16x16x32_bf16(A1, bh, acc[1][t], 0, 0, 0);
      acc[1][t] = __builtin_amdgcn_mfma_f32_16x16x32_bf16(A1, bl, acc[1][t], 0, 0, 0);
    }
  }

#pragma unroll
  for (int mt = 0; mt < 2; ++mt)
#pragma unroll
    for (int reg = 0; reg < 4; ++reg) {
      const int r = row0 + mt * 16 + quad * 4 + reg;
      if (r < M) {
        unsigned short* yp = Y + (size_t)r * CF + mrow;
#pragma unroll
        for (int t = 0; t < 8; ++t) yp[t * 16] = bf16rne(acc[mt][t][reg]);
      }
    }
}

// --------------------------- scan kernels (unchanged) ----------------------
__global__ __launch_bounds__(256)
void scan_block(const int* __restrict__ cnt, int* __restrict__ ptr,
                int* __restrict__ blksum, int n) {
  __shared__ int sdata[256];
  const int t = threadIdx.x;
  const int idx = blockIdx.x * 1024 + t * 4;
  int v[4];
#pragma unroll
  for (int k = 0; k < 4; ++k) v[k] = (idx + k < n) ? cnt[idx + k] : 0;
  int tsum = v[0] + v[1] + v[2] + v[3];
  sdata[t] = tsum;
  __syncthreads();
  for (int off = 1; off < 256; off <<= 1) {
    int x = (t >= off) ? sdata[t - off] : 0;
    __syncthreads();
    sdata[t] += x;
    __syncthreads();
  }
  if (t == 255) blksum[blockIdx.x] = sdata[255];
  int run = sdata[t] - tsum;
#pragma unroll
  for (int k = 0; k < 4; ++k) {
    if (idx + k < n) ptr[idx + k] = run;
    run += v[k];
  }
}

__global__ void scan_sums(int* blksum, int nb) {
  if (threadIdx.x == 0) {
    int run = 0;
    for (int i = 0; i < nb; ++i) { int c = blksum[i]; blksum[i] = run; run += c; }
  }
}

__global__ __launch_bounds__(256)
void scan_add(int* __restrict__ ptr, int* __restrict__ cursor,
              const int* __restrict__ blkoff, int n) {
  const int off = blkoff[blockIdx.x];
  const int base = blockIdx.x * 1024 + threadIdx.x;
#pragma unroll
  for (int k = 0; k < 4; ++k) {
    int i = base + k * 256;
    if (i < n) { int v = ptr[i] + off; ptr[i] = v; cursor[i] = v; }
  }
}

// --------------------- two-level LDS counting-sort CSR build ---------------
// Pass A: per-(bucket,chunk-block) counts via LDS histogram (no global atomics).
// cnt layout: cnt[bucket*NPASSBLK + blk]; tail cell cnt[nbuk*NPASSBLK] = 0.
__global__ __launch_bounds__(256)
void bucket_count(const int* __restrict__ rows, int* __restrict__ cnt,
                  int nnz, int nbuk, int chunk) {
  extern __shared__ int lh[];
  const int blk = blockIdx.x, tid = threadIdx.x;
  for (int b = tid; b < nbuk; b += 256) lh[b] = 0;
  __syncthreads();
  const int i0 = blk * chunk;
  const int i1 = min(i0 + chunk, nnz);
  for (int i = i0 + tid; i < i1; i += 256) atomicAdd(&lh[rows[i] >> RB_SHIFT], 1);
  __syncthreads();
  for (int b = tid; b < nbuk; b += 256) cnt[b * NPASSBLK + blk] = lh[b];
  if (blk == 0 && tid == 0) cnt[nbuk * NPASSBLK] = 0;
}

// Pass C: scatter edges into bucket-grouped temp prT, writes land in
// contiguous per-(bucket,block) runs (~16 el = 128 B) instead of random 8 B.
// Row-within-bucket (6 bits) packed into high bits of col (col < 2^26).
__global__ __launch_bounds__(256)
void bucket_scatter(const int* __restrict__ rows, const int* __restrict__ cols,
                    const float* __restrict__ vals, const int* __restrict__ S,
                    int2* __restrict__ prT, int nnz, int nbuk, int chunk) {
  extern __shared__ int lcur[];
  const int blk = blockIdx.x, tid = threadIdx.x;
  for (int b = tid; b < nbuk; b += 256) lcur[b] = S[b * NPASSBLK + blk];
  __syncthreads();
  const int i0 = blk * chunk;
  const int i1 = min(i0 + chunk, nnz);
  for (int i = i0 + tid; i < i1; i += 256) {
    const int r = rows[i];
    const int p = atomicAdd(&lcur[r >> RB_SHIFT], 1);
    prT[p] = make_int2(cols[i] | ((r & (RB - 1)) << 26), __float_as_int(vals[i]));
  }
}

// Pass D: per-bucket in-LDS counting sort (64 row bins) -> exact CSR pr + ptr.
// Writes are ~row-nnz runs (avg 32 el = 256 B for adj), fully clustered.
__global__ __launch_bounds__(256)
void bucket_to_csr(const int* __restrict__ S, const int2* __restrict__ prT,
                   int2* __restrict__ pr, int* __restrict__ ptr, int n_rows) {
  __shared__ int h[RB + 1];
  __shared__ int cur[RB];
  const int b = blockIdx.x, tid = threadIdx.x;
  const int js = S[b * NPASSBLK];
  const int je = S[(b + 1) * NPASSBLK];
  if (tid <= RB) h[tid] = 0;
  __syncthreads();
  for (int j = js + tid; j < je; j += 256)
    atomicAdd(&h[((unsigned)prT[j].x) >> 26], 1);
  __syncthreads();
  if (tid == 0) {
    int run = js;
    for (int t = 0; t < RB; ++t) { int c = h[t]; h[t] = run; cur[t] = run; run += c; }
    h[RB] = run;   // == je
  }
  __syncthreads();
  if (tid <= RB) {
    const int r = b * RB + tid;
    if (r <= n_rows) ptr[r] = h[tid];   // covers ptr[n_rows] via inclusive tid
  }
  for (int j = js + tid; j < je; j += 256) {
    const int2 e = prT[j];
    const unsigned cw = (unsigned)e.x;
    const int p = atomicAdd(&cur[cw >> 26], 1);
    pr[p] = make_int2((int)(cw & 0x03FFFFFFu), e.y);
  }
}

// ----------------------------- CSR SpMM (bf16 features) --------------------
template <bool SIG>
__global__ __launch_bounds__(256)
void csr_spmm_b16(const int* __restrict__ ptr, const int2* __restrict__ pr,
                  const unsigned* __restrict__ X, unsigned* __restrict__ Y,
                  int n_rows) {
  const int wid = (blockIdx.x << 2) + (threadIdx.x >> 6);
  if (wid >= n_rows) return;
  const int lane = threadIdx.x & 63;
  int j = ptr[wid];
  const int je = ptr[wid + 1];
  float2 acc = make_float2(0.f, 0.f);
  for (; j + 4 <= je; j += 4) {
    int2 p0 = pr[j], p1 = pr[j + 1], p2 = pr[j + 2], p3 = pr[j + 3];
    float2 a0 = bf2f(X[(size_t)p0.x * 64 + lane]);
    float2 a1 = bf2f(X[(size_t)p1.x * 64 + lane]);
    float2 a2 = bf2f(X[(size_t)p2.x * 64 + lane]);
    float2 a3 = bf2f(X[(size_t)p3.x * 64 + lane]);
    float v0 = __int_as_float(p0.y), v1 = __int_as_float(p1.y);
    float v2 = __int_as_float(p2.y), v3 = __int_as_float(p3.y);
    acc.x += v0 * a0.x + v1 * a1.x + v2 * a2.x + v3 * a3.x;
    acc.y += v0 * a0.y + v1 * a1.y + v2 * a2.y + v3 * a3.y;
  }
  for (; j < je; ++j) {
    int2 p = pr[j];
    float2 a = bf2f(X[(size_t)p.x * 64 + lane]);
    float v = __int_as_float(p.y);
    acc.x += v * a.x;
    acc.y += v * a.y;
  }
  if (SIG) {
    acc.x = 1.f / (1.f + __expf(-acc.x));
    acc.y = 1.f / (1.f + __expf(-acc.y));
  }
  Y[(size_t)wid * 64 + lane] =
      (unsigned)bf16rne(acc.x) | ((unsigned)bf16rne(acc.y) << 16);
}

// Fused level-2 merge: out[r] = sigmoid( adj-seg(XA) + inc-seg(XB) ), f32 out.
__global__ __launch_bounds__(256)
void csr_spmm2_sig(const int* __restrict__ ptrA, const int2* __restrict__ prA,
                   const unsigned* __restrict__ XA,
                   const int* __restrict__ ptrB, const int2* __restrict__ prB,
                   const unsigned* __restrict__ XB,
                   float* __restrict__ Y, int n_rows) {
  const int wid = (blockIdx.x << 2) + (threadIdx.x >> 6);
  if (wid >= n_rows) return;
  const int lane = threadIdx.x & 63;
  float2 acc = make_float2(0.f, 0.f);
  {
    int j = ptrA[wid];
    const int je = ptrA[wid + 1];
    for (; j + 4 <= je; j += 4) {
      int2 p0 = prA[j], p1 = prA[j + 1], p2 = prA[j + 2], p3 = prA[j + 3];
      float2 a0 = bf2f(XA[(size_t)p0.x * 64 + lane]);
      float2 a1 = bf2f(XA[(size_t)p1.x * 64 + lane]);
      float2 a2 = bf2f(XA[(size_t)p2.x * 64 + lane]);
      float2 a3 = bf2f(XA[(size_t)p3.x * 64 + lane]);
      float v0 = __int_as_float(p0.y), v1 = __int_as_float(p1.y);
      float v2 = __int_as_float(p2.y), v3 = __int_as_float(p3.y);
      acc.x += v0 * a0.x + v1 * a1.x + v2 * a2.x + v3 * a3.x;
      acc.y += v0 * a0.y + v1 * a1.y + v2 * a2.y + v3 * a3.y;
    }
    for (; j < je; ++j) {
      int2 p = prA[j];
      float2 a = bf2f(XA[(size_t)p.x * 64 + lane]);
      float v = __int_as_float(p.y);
      acc.x += v * a.x;
      acc.y += v * a.y;
    }
  }
  {
    int j = ptrB[wid];
    const int je = ptrB[wid + 1];
    for (; j + 2 <= je; j += 2) {
      int2 p0 = prB[j], p1 = prB[j + 1];
      float2 a0 = bf2f(XB[(size_t)p0.x * 64 + lane]);
      float2 a1 = bf2f(XB[(size_t)p1.x * 64 + lane]);
      float v0 = __int_as_float(p0.y), v1 = __int_as_float(p1.y);
      acc.x += v0 * a0.x + v1 * a1.x;
      acc.y += v0 * a0.y + v1 * a1.y;
    }
    for (; j < je; ++j) {
      int2 p = prB[j];
      float2 a = bf2f(XB[(size_t)p.x * 64 + lane]);
      float v = __int_as_float(p.y);
      acc.x += v * a.x;
      acc.y += v * a.y;
    }
  }
  acc.x = 1.f / (1.f + __expf(-acc.x));
  acc.y = 1.f / (1.f + __expf(-acc.y));
  ((float2*)Y)[(size_t)wid * 64 + lane] = acc;
}

// ---------------------------------------------------------------------------
extern "C" void kernel_launch(void* const* d_in, const int* in_sizes, int n_in,
                              void* d_out, int out_size, void* d_ws, size_t ws_size,
                              hipStream_t stream) {
  const float* x      = (const float*)d_in[0];
  const float* W1_00  = (const float*)d_in[1];
  const float* W1_01  = (const float*)d_in[2];
  const float* W2_00  = (const float*)d_in[3];
  const float* W2_10  = (const float*)d_in[4];
  const int*   adj_rows = (const int*)d_in[5];
  const int*   adj_cols = (const int*)d_in[6];
  const float* adj_vals = (const float*)d_in[7];
  const int*   inc_rows = (const int*)d_in[8];
  const int*   inc_cols = (const int*)d_in[9];
  const float* inc_vals = (const float*)d_in[10];

  const int adj_nnz = in_sizes[5];       // 3,200,000
  const int inc_nnz = in_sizes[8];       // 400,000
  const int NN = in_sizes[0] / CF;       // 100,000 nodes
  const int EN = 200000;                 // edges (problem constant)

  const long long NE = (long long)NN * CF;   // node features
  const long long EE = (long long)EN * CF;   // edge features
  const int PN = ((NN + 2) & ~1);            // padded (8B-align int2 arrays)
  const int PE = ((EN + 2) & ~1);

  // ---- workspace layout (unchanged offsets; cur_* now unused) ----
  unsigned short* tA = (unsigned short*)d_ws;   // NE bf16 : t2; prT alias at build
  unsigned short* n1 = tA + NE;                 // NE bf16 : sig l1 -> t3
  unsigned short* e1 = n1 + NE;                 // EE bf16 : sig l1 -> t4; cnt/S alias at build
  int*   ptr_a = (int*)(e1 + EE);
  int*   cur_a = ptr_a + PN;                    // (unused, layout stability)
  int2*  pr_a  = (int2*)(cur_a + PN);
  int*   ptr_e = (int*)(pr_a + adj_nnz);
  int*   cur_e = ptr_e + PE;                    // (unused)
  int2*  pr_e  = (int2*)(cur_e + PE);
  int*   ptr_i = (int*)(pr_e + inc_nnz);
  int*   cur_i = ptr_i + PN;                    // (unused)
  int2*  pr_i  = (int2*)(cur_i + PN);
  int*   blks  = (int*)(pr_i + inc_nnz);        // 1024 ints
  short* wp = (short*)(((uintptr_t)(blks + 1024) + 63) & ~(uintptr_t)63);
  short* w00h = wp;            short* w00l = wp + 16384;
  short* w01h = wp + 2*16384;  short* w01l = wp + 3*16384;
  short* w20h = wp + 4*16384;  short* w20l = wp + 5*16384;
  short* w21h = wp + 6*16384;  short* w21l = wp + 7*16384;

  // build-time scratch aliased onto feature buffers (dead until GEMMs):
  int2* prT  = (int2*)tA;        // <= adj_nnz*8 B  (= tA region, spill->n1 safe)
  int*  cntA = (int*)e1;         // <= ~400,065 ints
  int*  SA   = cntA + 400064;    // exclusive-scanned offsets (8B-aligned offset)

  unsigned short* t1 = (unsigned short*)d_out;  // bf16 scratch; dead before final write
  float* outf = (float*)d_out;

  const dim3 blk(256);
  const int gN = (NN + 63) / 64;
  const int gE = (EN + 63) / 64;

  // ---- pack weights ----
  pack_w<<<8, blk, 0, stream>>>(W1_00, w00h, w00l);
  pack_w<<<8, blk, 0, stream>>>(W1_01, w01h, w01l);
  pack_w<<<8, blk, 0, stream>>>(W2_00, w20h, w20l);
  pack_w<<<8, blk, 0, stream>>>(W2_10, w21h, w21l);

  // ---- CSR builds via two-level LDS counting sort ----
  auto build = [&](const int* rows, const int* cols, const float* vals,
                   int nnz, int n_rows, int* ptr, int2* pr) {
    const int nbuk  = (n_rows + RB - 1) >> RB_SHIFT;
    const int chunk = (nnz + NPASSBLK - 1) / NPASSBLK;
    const int nS    = nbuk * NPASSBLK + 1;
    const int nbS   = (nS + 1023) / 1024;
    bucket_count<<<NPASSBLK, blk, nbuk * 4, stream>>>(rows, cntA, nnz, nbuk, chunk);
    scan_block<<<nbS, blk, 0, stream>>>(cntA, SA, blks, nS);
    scan_sums<<<1, 64, 0, stream>>>(blks, nbS);
    scan_add<<<nbS, blk, 0, stream>>>(SA, cntA /*dummy cursor*/, blks, nS);
    bucket_scatter<<<NPASSBLK, blk, nbuk * 4, stream>>>(rows, cols, vals, SA, prT, nnz, nbuk, chunk);
    bucket_to_csr<<<nbuk, blk, 0, stream>>>(SA, prT, pr, ptr, n_rows);
  };

  build(adj_rows, adj_cols, adj_vals, adj_nnz, NN, ptr_a, pr_a);  // adj by rows
  build(inc_cols, inc_rows, inc_vals, inc_nnz, EN, ptr_e, pr_e);  // B1^T: rows=edges
  build(inc_rows, inc_cols, inc_vals, inc_nnz, NN, ptr_i, pr_i);  // B1: rows=nodes

  // ---- level 1 GEMMs (f32 x -> bf16 out) ----
  gemm_f32_b16<<<gN, dim3(128), 0, stream>>>(x, w00h, w00l, t1, NN);
  gemm_f32_b16<<<gN, dim3(128), 0, stream>>>(x, w01h, w01l, tA, NN);

  // ---- level 1 SpMMs (bf16 gather, fused sigmoid, bf16 out) ----
  csr_spmm_b16<true><<<(NN + 3) / 4, blk, 0, stream>>>(ptr_a, pr_a, (const unsigned*)t1, (unsigned*)n1, NN);
  csr_spmm_b16<true><<<(EN + 3) / 4, blk, 0, stream>>>(ptr_e, pr_e, (const unsigned*)tA, (unsigned*)e1, EN);

  // ---- level 2 GEMMs (bf16 in/out, in-place) ----
  gemm_b16_b16<<<gN, dim3(128), 0, stream>>>(n1, w20h, w20l, n1, NN);
  gemm_b16_b16<<<gE, dim3(128), 0, stream>>>(e1, w21h, w21l, e1, EN);

  // ---- fused level-2 SpMMs + merge sigmoid (f32 out) ----
  csr_spmm2_sig<<<(NN + 3) / 4, blk, 0, stream>>>(ptr_a, pr_a, (const unsigned*)n1,
                                                  ptr_i, pr_i, (const unsigned*)e1, outf, NN);
}

// Round 2
// 907.632 us; speedup vs baseline: 1.1253x; 1.0210x over previous
//
#include <hip/hip_runtime.h>

// HSN layer: out = sigmoid( A0 @ (sig(A0 @ (x W1_00)) W2_00) + B1 @ (sig(B1^T @ (x W1_01)) W2_10) )
// C = 128 fixed. CSR-gather SpMM (no f32 atomics) + MFMA GEMMs.
// Intermediate features in bf16 (256 B/row) to halve gather traffic.
// CSR build: two-level LDS counting sort (no global atomics, clustered writes).
// SpMM: "quad-gather" layout -- 4 lane-groups x 16 lanes, each lane loads a
// uint4 (8 features); 1 KB/instruction in flight, 4x fewer VMEM issues than
// the 1-uint/lane form whose dependent pr->gather chain capped BW at 3.2 TB/s.

#define CF 128
#define RB 64          // rows per bucket (2^RB_SHIFT)
#define RB_SHIFT 6
#define NPASSBLK 128   // blocks (chunks) in count/scatter passes

typedef __attribute__((ext_vector_type(8))) short bf16x8;
typedef __attribute__((ext_vector_type(4))) float f32x4;

// f32 -> bf16 round-to-nearest-even (finite inputs)
__device__ __forceinline__ unsigned short bf16rne(float f) {
  unsigned u = __float_as_uint(f);
  u += 0x7FFFu + ((u >> 16) & 1u);
  return (unsigned short)(u >> 16);
}
// packed pair of bf16 (low short = even feature) -> two floats
__device__ __forceinline__ float2 bf2f(unsigned u) {
  return make_float2(__uint_as_float(u << 16), __uint_as_float(u & 0xFFFF0000u));
}
// split f32 -> bf16 hi (trunc) + bf16 lo (residual)
__device__ __forceinline__ void splitf(float f, short& h, short& l) {
  unsigned u = __float_as_uint(f);
  h = (short)(u >> 16);
  float fh = __uint_as_float(u & 0xFFFF0000u);
  float r = f - fh;
  l = (short)(__float_as_uint(r) >> 16);
}

// ---------------------------------------------------------------------------
// Pack 4x W[128][128] f32 (row-major [k][n]) into mfma_f32_16x16x32_bf16
// B-fragment order: frag[(s*8+t)*64+lane][j] = W[s*32+(lane>>4)*8+j][t*16+(lane&15)]
// One launch packs all four weights (blockIdx>>3 selects W).
// ---------------------------------------------------------------------------
__global__ __launch_bounds__(256)
void pack_w4(const float* __restrict__ W0, const float* __restrict__ W1,
             const float* __restrict__ W2, const float* __restrict__ W3,
             short* __restrict__ wp) {
  const int w = blockIdx.x >> 3;
  const float* W = (w == 0) ? W0 : (w == 1) ? W1 : (w == 2) ? W2 : W3;
  short* hi = wp + (size_t)w * 32768;
  short* lo = hi + 16384;
  const int tid = (blockIdx.x & 7) * 256 + threadIdx.x;   // 0..2047
  const int lane = tid & 63;
  const int t = (tid >> 6) & 7;
  const int s = tid >> 9;
  const int n = t * 16 + (lane & 15);
  const int k0 = s * 32 + ((lane >> 4) << 3);
  short* hp = hi + (size_t)tid * 8;
  short* lp = lo + (size_t)tid * 8;
#pragma unroll
  for (int j = 0; j < 8; ++j) {
    short h, l;
    splitf(W[(size_t)(k0 + j) * CF + n], h, l);
    hp[j] = h;
    lp[j] = l;
  }
}

// ---------------------------------------------------------------------------
// GEMM (f32 in, bf16 out): Y = X @ W, 3-term hi/lo split MFMA.
// ---------------------------------------------------------------------------
__global__ __launch_bounds__(128)
void gemm_f32_b16(const float* __restrict__ X, const short* __restrict__ Whi,
                  const short* __restrict__ Wlo, unsigned short* __restrict__ Y,
                  int M) {
  const int wave = threadIdx.x >> 6;
  const int lane = threadIdx.x & 63;
  const int mrow = lane & 15;
  const int quad = lane >> 4;
  const int row0 = blockIdx.x * 64 + wave * 32;

  const bf16x8* WH = (const bf16x8*)Whi;
  const bf16x8* WL = (const bf16x8*)Wlo;

  f32x4 acc[2][8];
#pragma unroll
  for (int mt = 0; mt < 2; ++mt)
#pragma unroll
    for (int t = 0; t < 8; ++t) acc[mt][t] = (f32x4){0.f, 0.f, 0.f, 0.f};

  int rA0 = row0 + mrow;      if (rA0 > M - 1) rA0 = M - 1;
  int rA1 = row0 + 16 + mrow; if (rA1 > M - 1) rA1 = M - 1;
  const float* xp0 = X + (size_t)rA0 * CF + quad * 8;
  const float* xp1 = X + (size_t)rA1 * CF + quad * 8;

#pragma unroll
  for (int s = 0; s < 4; ++s) {
    bf16x8 Ah[2], Al[2];
    const float* p = xp0 + s * 32;
#pragma unroll
    for (int j = 0; j < 8; ++j) { short h, l; splitf(p[j], h, l); Ah[0][j] = h; Al[0][j] = l; }
    p = xp1 + s * 32;
#pragma unroll
    for (int j = 0; j < 8; ++j) { short h, l; splitf(p[j], h, l); Ah[1][j] = h; Al[1][j] = l; }
#pragma unroll
    for (int t = 0; t < 8; ++t) {
      const bf16x8 bh = WH[(s * 8 + t) * 64 + lane];
      const bf16x8 bl = WL[(s * 8 + t) * 64 + lane];
#pragma unroll
      for (int mt = 0; mt < 2; ++mt) {
        acc[mt][t] = __builtin_amdgcn_mfma_f32_16x16x32_bf16(Ah[mt], bh, acc[mt][t], 0, 0, 0);
        acc[mt][t] = __builtin_amdgcn_mfma_f32_16x16x32_bf16(Al[mt], bh, acc[mt][t], 0, 0, 0);
        acc[mt][t] = __builtin_amdgcn_mfma_f32_16x16x32_bf16(Ah[mt], bl, acc[mt][t], 0, 0, 0);
      }
    }
  }

#pragma unroll
  for (int mt = 0; mt < 2; ++mt)
#pragma unroll
    for (int reg = 0; reg < 4; ++reg) {
      const int r = row0 + mt * 16 + quad * 4 + reg;
      if (r < M) {
        unsigned short* yp = Y + (size_t)r * CF + mrow;
#pragma unroll
        for (int t = 0; t < 8; ++t) yp[t * 16] = bf16rne(acc[mt][t][reg]);
      }
    }
}

// ---------------------------------------------------------------------------
// GEMM (bf16 in, bf16 out): Y = X @ W, 2-term (W split) MFMA. In-place safe.
// ---------------------------------------------------------------------------
__global__ __launch_bounds__(128)
void gemm_b16_b16(const unsigned short* __restrict__ X,
                  const short* __restrict__ Whi, const short* __restrict__ Wlo,
                  unsigned short* __restrict__ Y, int M) {
  const int wave = threadIdx.x >> 6;
  const int lane = threadIdx.x & 63;
  const int mrow = lane & 15;
  const int quad = lane >> 4;
  const int row0 = blockIdx.x * 64 + wave * 32;

  const bf16x8* WH = (const bf16x8*)Whi;
  const bf16x8* WL = (const bf16x8*)Wlo;

  f32x4 acc[2][8];
#pragma unroll
  for (int mt = 0; mt < 2; ++mt)
#pragma unroll
    for (int t = 0; t < 8; ++t) acc[mt][t] = (f32x4){0.f, 0.f, 0.f, 0.f};

  int rA0 = row0 + mrow;      if (rA0 > M - 1) rA0 = M - 1;
  int rA1 = row0 + 16 + mrow; if (rA1 > M - 1) rA1 = M - 1;
  const bf16x8* xp0 = (const bf16x8*)(X + (size_t)rA0 * CF + quad * 8);
  const bf16x8* xp1 = (const bf16x8*)(X + (size_t)rA1 * CF + quad * 8);

#pragma unroll
  for (int s = 0; s < 4; ++s) {
    bf16x8 A0 = xp0[s * 4];
    bf16x8 A1 = xp1[s * 4];
#pragma unroll
    for (int t = 0; t < 8; ++t) {
      const bf16x8 bh = WH[(s * 8 + t) * 64 + lane];
      const bf16x8 bl = WL[(s * 8 + t) * 64 + lane];
      acc[0][t] = __builtin_amdgcn_mfma_f32_16x16x32_bf16(A0, bh, acc[0][t], 0, 0, 0);
      acc[0][t] = __builtin_amdgcn_mfma_f32_16x16x32_bf16(A0, bl, acc[0][t], 0, 0, 0);
      acc[1][t] = __builtin_amdgcn_mfma_f32_16x16x32_bf16(A1, bh, acc[1][t], 0, 0, 0);
      acc[1][t] = __builtin_amdgcn_mfma_f32_16x16x32_bf16(A1, bl, acc[1][t], 0, 0, 0);
    }
  }

#pragma unroll
  for (int mt = 0; mt < 2; ++mt)
#pragma unroll
    for (int reg = 0; reg < 4; ++reg) {
      const int r = row0 + mt * 16 + quad * 4 + reg;
      if (r < M) {
        unsigned short* yp = Y + (size_t)r * CF + mrow;
#pragma unroll
        for (int t = 0; t < 8; ++t) yp[t * 16] = bf16rne(acc[mt][t][reg]);
      }
    }
}

// --------------------------- scan kernels ----------------------------------
__global__ __launch_bounds__(256)
void scan_block(const int* __restrict__ cnt, int* __restrict__ ptr,
                int* __restrict__ blksum, int n) {
  __shared__ int sdata[256];
  const int t = threadIdx.x;
  const int idx = blockIdx.x * 1024 + t * 4;
  int v[4];
#pragma unroll
  for (int k = 0; k < 4; ++k) v[k] = (idx + k < n) ? cnt[idx + k] : 0;
  int tsum = v[0] + v[1] + v[2] + v[3];
  sdata[t] = tsum;
  __syncthreads();
  for (int off = 1; off < 256; off <<= 1) {
    int x = (t >= off) ? sdata[t - off] : 0;
    __syncthreads();
    sdata[t] += x;
    __syncthreads();
  }
  if (t == 255) blksum[blockIdx.x] = sdata[255];
  int run = sdata[t] - tsum;
#pragma unroll
  for (int k = 0; k < 4; ++k) {
    if (idx + k < n) ptr[idx + k] = run;
    run += v[k];
  }
}

__global__ void scan_sums(int* blksum, int nb) {
  if (threadIdx.x == 0) {
    int run = 0;
    for (int i = 0; i < nb; ++i) { int c = blksum[i]; blksum[i] = run; run += c; }
  }
}

__global__ __launch_bounds__(256)
void scan_add(int* __restrict__ ptr, int* __restrict__ cursor,
              const int* __restrict__ blkoff, int n) {
  const int off = blkoff[blockIdx.x];
  const int base = blockIdx.x * 1024 + threadIdx.x;
#pragma unroll
  for (int k = 0; k < 4; ++k) {
    int i = base + k * 256;
    if (i < n) { int v = ptr[i] + off; ptr[i] = v; cursor[i] = v; }
  }
}

// --------------------- two-level LDS counting-sort CSR build ---------------
__global__ __launch_bounds__(256)
void bucket_count(const int* __restrict__ rows, int* __restrict__ cnt,
                  int nnz, int nbuk, int chunk) {
  extern __shared__ int lh[];
  const int blk = blockIdx.x, tid = threadIdx.x;
  for (int b = tid; b < nbuk; b += 256) lh[b] = 0;
  __syncthreads();
  const int i0 = blk * chunk;
  const int i1 = min(i0 + chunk, nnz);
  for (int i = i0 + tid; i < i1; i += 256) atomicAdd(&lh[rows[i] >> RB_SHIFT], 1);
  __syncthreads();
  for (int b = tid; b < nbuk; b += 256) cnt[b * NPASSBLK + blk] = lh[b];
  if (blk == 0 && tid == 0) cnt[nbuk * NPASSBLK] = 0;
}

__global__ __launch_bounds__(256)
void bucket_scatter(const int* __restrict__ rows, const int* __restrict__ cols,
                    const float* __restrict__ vals, const int* __restrict__ S,
                    int2* __restrict__ prT, int nnz, int nbuk, int chunk) {
  extern __shared__ int lcur[];
  const int blk = blockIdx.x, tid = threadIdx.x;
  for (int b = tid; b < nbuk; b += 256) lcur[b] = S[b * NPASSBLK + blk];
  __syncthreads();
  const int i0 = blk * chunk;
  const int i1 = min(i0 + chunk, nnz);
  for (int i = i0 + tid; i < i1; i += 256) {
    const int r = rows[i];
    const int p = atomicAdd(&lcur[r >> RB_SHIFT], 1);
    prT[p] = make_int2(cols[i] | ((r & (RB - 1)) << 26), __float_as_int(vals[i]));
  }
}

__global__ __launch_bounds__(256)
void bucket_to_csr(const int* __restrict__ S, const int2* __restrict__ prT,
                   int2* __restrict__ pr, int* __restrict__ ptr, int n_rows) {
  __shared__ int h[RB + 1];
  __shared__ int cur[RB];
  const int b = blockIdx.x, tid = threadIdx.x;
  const int js = S[b * NPASSBLK];
  const int je = S[(b + 1) * NPASSBLK];
  if (tid <= RB) h[tid] = 0;
  __syncthreads();
  for (int j = js + tid; j < je; j += 256)
    atomicAdd(&h[((unsigned)prT[j].x) >> 26], 1);
  __syncthreads();
  if (tid == 0) {
    int run = js;
    for (int t = 0; t < RB; ++t) { int c = h[t]; h[t] = run; cur[t] = run; run += c; }
    h[RB] = run;   // == je
  }
  __syncthreads();
  if (tid <= RB) {
    const int r = b * RB + tid;
    if (r <= n_rows) ptr[r] = h[tid];
  }
  for (int j = js + tid; j < je; j += 256) {
    const int2 e = prT[j];
    const unsigned cw = (unsigned)e.x;
    const int p = atomicAdd(&cur[cw >> 26], 1);
    pr[p] = make_int2((int)(cw & 0x03FFFFFFu), e.y);
  }
}

// ----------------------------- CSR SpMM (quad-gather) ----------------------
// Wave = 4 groups x 16 lanes. Group g handles nnz j+g; lane q loads uint4
// (features 8q..8q+7). UNR iterations' pr loads all issue before gathers ->
// up to UNR KB in flight per wave. Tail nnz masked to (row 0, v=0).
template <int UNR>
__device__ __forceinline__ void seg_accum(const int* __restrict__ ptr,
                                          const int2* __restrict__ pr,
                                          const unsigned* __restrict__ Xq,
                                          int wid, int g, float* acc) {
  int j = ptr[wid];
  const int je = ptr[wid + 1];
  for (; j < je; j += 4 * UNR) {
    int2 p[UNR];
#pragma unroll
    for (int u = 0; u < UNR; ++u) {
      const int jj = j + 4 * u + g;
      p[u] = (jj < je) ? pr[jj] : make_int2(0, 0);
    }
    uint4 d[UNR];
#pragma unroll
    for (int u = 0; u < UNR; ++u)
      d[u] = *(const uint4*)(Xq + (size_t)p[u].x * 64);
#pragma unroll
    for (int u = 0; u < UNR; ++u) {
      const float v = __int_as_float(p[u].y);
      float2 f;
      f = bf2f(d[u].x); acc[0] += v * f.x; acc[1] += v * f.y;
      f = bf2f(d[u].y); acc[2] += v * f.x; acc[3] += v * f.y;
      f = bf2f(d[u].z); acc[4] += v * f.x; acc[5] += v * f.y;
      f = bf2f(d[u].w); acc[6] += v * f.x; acc[7] += v * f.y;
    }
  }
}

template <bool SIG, int UNR>
__global__ __launch_bounds__(256)
void csr_spmm_b16(const int* __restrict__ ptr, const int2* __restrict__ pr,
                  const unsigned* __restrict__ X, unsigned* __restrict__ Y,
                  int n_rows) {
  const int wid = (blockIdx.x << 2) + (threadIdx.x >> 6);
  if (wid >= n_rows) return;
  const int lane = threadIdx.x & 63;
  const int g = lane >> 4;
  const int q = lane & 15;
  float acc[8];
#pragma unroll
  for (int k = 0; k < 8; ++k) acc[k] = 0.f;
  seg_accum<UNR>(ptr, pr, X + q * 4, wid, g, acc);
#pragma unroll
  for (int k = 0; k < 8; ++k) acc[k] += __shfl_xor(acc[k], 16);
#pragma unroll
  for (int k = 0; k < 8; ++k) acc[k] += __shfl_xor(acc[k], 32);
  if (g == 0) {
    if (SIG) {
#pragma unroll
      for (int k = 0; k < 8; ++k) acc[k] = 1.f / (1.f + __expf(-acc[k]));
    }
    uint4 o;
    o.x = (unsigned)bf16rne(acc[0]) | ((unsigned)bf16rne(acc[1]) << 16);
    o.y = (unsigned)bf16rne(acc[2]) | ((unsigned)bf16rne(acc[3]) << 16);
    o.z = (unsigned)bf16rne(acc[4]) | ((unsigned)bf16rne(acc[5]) << 16);
    o.w = (unsigned)bf16rne(acc[6]) | ((unsigned)bf16rne(acc[7]) << 16);
    *(uint4*)(Y + (size_t)wid * 64 + q * 4) = o;
  }
}

// Fused level-2 merge: out[r] = sigmoid( adj-seg(XA) + inc-seg(XB) ), f32 out.
__global__ __launch_bounds__(256)
void csr_spmm2_sig(const int* __restrict__ ptrA, const int2* __restrict__ prA,
                   const unsigned* __restrict__ XA,
                   const int* __restrict__ ptrB, const int2* __restrict__ prB,
                   const unsigned* __restrict__ XB,
                   float* __restrict__ Y, int n_rows) {
  const int wid = (blockIdx.x << 2) + (threadIdx.x >> 6);
  if (wid >= n_rows) return;
  const int lane = threadIdx.x & 63;
  const int g = lane >> 4;
  const int q = lane & 15;
  float acc[8];
#pragma unroll
  for (int k = 0; k < 8; ++k) acc[k] = 0.f;
  seg_accum<4>(ptrA, prA, XA + q * 4, wid, g, acc);
  seg_accum<1>(ptrB, prB, XB + q * 4, wid, g, acc);
#pragma unroll
  for (int k = 0; k < 8; ++k) acc[k] += __shfl_xor(acc[k], 16);
#pragma unroll
  for (int k = 0; k < 8; ++k) acc[k] += __shfl_xor(acc[k], 32);
  if (g == 0) {
#pragma unroll
    for (int k = 0; k < 8; ++k) acc[k] = 1.f / (1.f + __expf(-acc[k]));
    float4* yp = (float4*)(Y + (size_t)wid * CF + q * 8);
    yp[0] = make_float4(acc[0], acc[1], acc[2], acc[3]);
    yp[1] = make_float4(acc[4], acc[5], acc[6], acc[7]);
  }
}

// ---------------------------------------------------------------------------
extern "C" void kernel_launch(void* const* d_in, const int* in_sizes, int n_in,
                              void* d_out, int out_size, void* d_ws, size_t ws_size,
                              hipStream_t stream) {
  const float* x      = (const float*)d_in[0];
  const float* W1_00  = (const float*)d_in[1];
  const float* W1_01  = (const float*)d_in[2];
  const float* W2_00  = (const float*)d_in[3];
  const float* W2_10  = (const float*)d_in[4];
  const int*   adj_rows = (const int*)d_in[5];
  const int*   adj_cols = (const int*)d_in[6];
  const float* adj_vals = (const float*)d_in[7];
  const int*   inc_rows = (const int*)d_in[8];
  const int*   inc_cols = (const int*)d_in[9];
  const float* inc_vals = (const float*)d_in[10];

  const int adj_nnz = in_sizes[5];       // 3,200,000
  const int inc_nnz = in_sizes[8];       // 400,000
  const int NN = in_sizes[0] / CF;       // 100,000 nodes
  const int EN = 200000;                 // edges (problem constant)

  const long long NE = (long long)NN * CF;   // node features
  const long long EE = (long long)EN * CF;   // edge features
  const int PN = ((NN + 2) & ~1);            // padded (8B-align int2 arrays)
  const int PE = ((EN + 2) & ~1);

  // ---- workspace layout ----
  unsigned short* tA = (unsigned short*)d_ws;   // NE bf16 : t2; prT alias at build
  unsigned short* n1 = tA + NE;                 // NE bf16 : sig l1 -> t3
  unsigned short* e1 = n1 + NE;                 // EE bf16 : sig l1 -> t4; cnt/S alias at build
  int*   ptr_a = (int*)(e1 + EE);
  int*   cur_a = ptr_a + PN;                    // (unused, layout stability)
  int2*  pr_a  = (int2*)(cur_a + PN);
  int*   ptr_e = (int*)(pr_a + adj_nnz);
  int*   cur_e = ptr_e + PE;                    // (unused)
  int2*  pr_e  = (int2*)(cur_e + PE);
  int*   ptr_i = (int*)(pr_e + inc_nnz);
  int*   cur_i = ptr_i + PN;                    // (unused)
  int2*  pr_i  = (int2*)(cur_i + PN);
  int*   blks  = (int*)(pr_i + inc_nnz);        // 1024 ints
  short* wp = (short*)(((uintptr_t)(blks + 1024) + 63) & ~(uintptr_t)63);
  short* w00h = wp;            short* w00l = wp + 16384;
  short* w01h = wp + 2*16384;  short* w01l = wp + 3*16384;
  short* w20h = wp + 4*16384;  short* w20l = wp + 5*16384;
  short* w21h = wp + 6*16384;  short* w21l = wp + 7*16384;

  // build-time scratch aliased onto feature buffers (dead until GEMMs):
  int2* prT  = (int2*)tA;        // <= adj_nnz*8 B  (= tA region, spill->n1 safe)
  int*  cntA = (int*)e1;         // <= ~400,065 ints
  int*  SA   = cntA + 400064;    // exclusive-scanned offsets

  unsigned short* t1 = (unsigned short*)d_out;  // bf16 scratch; dead before final write
  float* outf = (float*)d_out;

  const dim3 blk(256);
  const int gN = (NN + 63) / 64;
  const int gE = (EN + 63) / 64;

  // ---- pack weights (one launch, 4 matrices) ----
  pack_w4<<<32, blk, 0, stream>>>(W1_00, W1_01, W2_00, W2_10, wp);

  // ---- CSR builds via two-level LDS counting sort ----
  auto build = [&](const int* rows, const int* cols, const float* vals,
                   int nnz, int n_rows, int* ptr, int2* pr) {
    const int nbuk  = (n_rows + RB - 1) >> RB_SHIFT;
    const int chunk = (nnz + NPASSBLK - 1) / NPASSBLK;
    const int nS    = nbuk * NPASSBLK + 1;
    const int nbS   = (nS + 1023) / 1024;
    bucket_count<<<NPASSBLK, blk, nbuk * 4, stream>>>(rows, cntA, nnz, nbuk, chunk);
    scan_block<<<nbS, blk, 0, stream>>>(cntA, SA, blks, nS);
    scan_sums<<<1, 64, 0, stream>>>(blks, nbS);
    scan_add<<<nbS, blk, 0, stream>>>(SA, cntA /*dummy cursor*/, blks, nS);
    bucket_scatter<<<NPASSBLK, blk, nbuk * 4, stream>>>(rows, cols, vals, SA, prT, nnz, nbuk, chunk);
    bucket_to_csr<<<nbuk, blk, 0, stream>>>(SA, prT, pr, ptr, n_rows);
  };

  build(adj_rows, adj_cols, adj_vals, adj_nnz, NN, ptr_a, pr_a);  // adj by rows
  build(inc_cols, inc_rows, inc_vals, inc_nnz, EN, ptr_e, pr_e);  // B1^T: rows=edges
  build(inc_rows, inc_cols, inc_vals, inc_nnz, NN, ptr_i, pr_i);  // B1: rows=nodes

  // ---- level 1 GEMMs (f32 x -> bf16 out) ----
  gemm_f32_b16<<<gN, dim3(128), 0, stream>>>(x, w00h, w00l, t1, NN);
  gemm_f32_b16<<<gN, dim3(128), 0, stream>>>(x, w01h, w01l, tA, NN);

  // ---- level 1 SpMMs (bf16 quad-gather, fused sigmoid, bf16 out) ----
  csr_spmm_b16<true, 4><<<(NN + 3) / 4, blk, 0, stream>>>(ptr_a, pr_a, (const unsigned*)t1, (unsigned*)n1, NN);
  csr_spmm_b16<true, 1><<<(EN + 3) / 4, blk, 0, stream>>>(ptr_e, pr_e, (const unsigned*)tA, (unsigned*)e1, EN);

  // ---- level 2 GEMMs (bf16 in/out, in-place) ----
  gemm_b16_b16<<<gN, dim3(128), 0, stream>>>(n1, w20h, w20l, n1, NN);
  gemm_b16_b16<<<gE, dim3(128), 0, stream>>>(e1, w21h, w21l, e1, EN);

  // ---- fused level-2 SpMMs + merge sigmoid (f32 out) ----
  csr_spmm2_sig<<<(NN + 3) / 4, blk, 0, stream>>>(ptr_a, pr_a, (const unsigned*)n1,
                                                  ptr_i, pr_i, (const unsigned*)e1, outf, NN);
}

// Round 3
// 886.525 us; speedup vs baseline: 1.1520x; 1.0238x over previous
//
#include <hip/hip_runtime.h>

// HSN layer: out = sigmoid( A0 @ (sig(A0 @ (x W1_00)) W2_00) + B1 @ (sig(B1^T @ (x W1_01)) W2_10) )
// C = 128 fixed. CSR-gather SpMM (no f32 atomics) + MFMA GEMMs.
// Intermediate features in bf16 (256 B/row) to halve gather traffic.
// CSR build: two-level LDS counting sort (no global atomics, clustered writes).
//   R2 fix: count/scatter passes were 128 blocks x 256 thr (5% occupancy,
//   latency-bound at 137 us). Now 256 blocks x 512 thr (full chip, 8 waves/CU).
// SpMM: quad-gather layout (4 lane-groups x 16 lanes, uint4 per lane).

#define CF 128
#define RB 64          // rows per bucket (2^RB_SHIFT)
#define RB_SHIFT 6
#define NPASSBLK 256   // blocks (chunks) in count/scatter passes
#define BT 512         // threads per count/scatter block

typedef __attribute__((ext_vector_type(8))) short bf16x8;
typedef __attribute__((ext_vector_type(4))) float f32x4;

// f32 -> bf16 round-to-nearest-even (finite inputs)
__device__ __forceinline__ unsigned short bf16rne(float f) {
  unsigned u = __float_as_uint(f);
  u += 0x7FFFu + ((u >> 16) & 1u);
  return (unsigned short)(u >> 16);
}
// packed pair of bf16 (low short = even feature) -> two floats
__device__ __forceinline__ float2 bf2f(unsigned u) {
  return make_float2(__uint_as_float(u << 16), __uint_as_float(u & 0xFFFF0000u));
}
// split f32 -> bf16 hi (trunc) + bf16 lo (residual)
__device__ __forceinline__ void splitf(float f, short& h, short& l) {
  unsigned u = __float_as_uint(f);
  h = (short)(u >> 16);
  float fh = __uint_as_float(u & 0xFFFF0000u);
  float r = f - fh;
  l = (short)(__float_as_uint(r) >> 16);
}

// ---------------------------------------------------------------------------
// Pack 4x W[128][128] f32 (row-major [k][n]) into mfma_f32_16x16x32_bf16
// B-fragment order: frag[(s*8+t)*64+lane][j] = W[s*32+(lane>>4)*8+j][t*16+(lane&15)]
// ---------------------------------------------------------------------------
__global__ __launch_bounds__(256)
void pack_w4(const float* __restrict__ W0, const float* __restrict__ W1,
             const float* __restrict__ W2, const float* __restrict__ W3,
             short* __restrict__ wp) {
  const int w = blockIdx.x >> 3;
  const float* W = (w == 0) ? W0 : (w == 1) ? W1 : (w == 2) ? W2 : W3;
  short* hi = wp + (size_t)w * 32768;
  short* lo = hi + 16384;
  const int tid = (blockIdx.x & 7) * 256 + threadIdx.x;   // 0..2047
  const int lane = tid & 63;
  const int t = (tid >> 6) & 7;
  const int s = tid >> 9;
  const int n = t * 16 + (lane & 15);
  const int k0 = s * 32 + ((lane >> 4) << 3);
  short* hp = hi + (size_t)tid * 8;
  short* lp = lo + (size_t)tid * 8;
#pragma unroll
  for (int j = 0; j < 8; ++j) {
    short h, l;
    splitf(W[(size_t)(k0 + j) * CF + n], h, l);
    hp[j] = h;
    lp[j] = l;
  }
}

// ---------------------------------------------------------------------------
// GEMM (f32 in, bf16 out): Y = X @ W, 3-term hi/lo split MFMA.
// ---------------------------------------------------------------------------
__global__ __launch_bounds__(128)
void gemm_f32_b16(const float* __restrict__ X, const short* __restrict__ Whi,
                  const short* __restrict__ Wlo, unsigned short* __restrict__ Y,
                  int M) {
  const int wave = threadIdx.x >> 6;
  const int lane = threadIdx.x & 63;
  const int mrow = lane & 15;
  const int quad = lane >> 4;
  const int row0 = blockIdx.x * 64 + wave * 32;

  const bf16x8* WH = (const bf16x8*)Whi;
  const bf16x8* WL = (const bf16x8*)Wlo;

  f32x4 acc[2][8];
#pragma unroll
  for (int mt = 0; mt < 2; ++mt)
#pragma unroll
    for (int t = 0; t < 8; ++t) acc[mt][t] = (f32x4){0.f, 0.f, 0.f, 0.f};

  int rA0 = row0 + mrow;      if (rA0 > M - 1) rA0 = M - 1;
  int rA1 = row0 + 16 + mrow; if (rA1 > M - 1) rA1 = M - 1;
  const float* xp0 = X + (size_t)rA0 * CF + quad * 8;
  const float* xp1 = X + (size_t)rA1 * CF + quad * 8;

#pragma unroll
  for (int s = 0; s < 4; ++s) {
    bf16x8 Ah[2], Al[2];
    const float* p = xp0 + s * 32;
#pragma unroll
    for (int j = 0; j < 8; ++j) { short h, l; splitf(p[j], h, l); Ah[0][j] = h; Al[0][j] = l; }
    p = xp1 + s * 32;
#pragma unroll
    for (int j = 0; j < 8; ++j) { short h, l; splitf(p[j], h, l); Ah[1][j] = h; Al[1][j] = l; }
#pragma unroll
    for (int t = 0; t < 8; ++t) {
      const bf16x8 bh = WH[(s * 8 + t) * 64 + lane];
      const bf16x8 bl = WL[(s * 8 + t) * 64 + lane];
#pragma unroll
      for (int mt = 0; mt < 2; ++mt) {
        acc[mt][t] = __builtin_amdgcn_mfma_f32_16x16x32_bf16(Ah[mt], bh, acc[mt][t], 0, 0, 0);
        acc[mt][t] = __builtin_amdgcn_mfma_f32_16x16x32_bf16(Al[mt], bh, acc[mt][t], 0, 0, 0);
        acc[mt][t] = __builtin_amdgcn_mfma_f32_16x16x32_bf16(Ah[mt], bl, acc[mt][t], 0, 0, 0);
      }
    }
  }

#pragma unroll
  for (int mt = 0; mt < 2; ++mt)
#pragma unroll
    for (int reg = 0; reg < 4; ++reg) {
      const int r = row0 + mt * 16 + quad * 4 + reg;
      if (r < M) {
        unsigned short* yp = Y + (size_t)r * CF + mrow;
#pragma unroll
        for (int t = 0; t < 8; ++t) yp[t * 16] = bf16rne(acc[mt][t][reg]);
      }
    }
}

// ---------------------------------------------------------------------------
// GEMM (bf16 in, bf16 out): Y = X @ W, 2-term (W split) MFMA. In-place safe.
// ---------------------------------------------------------------------------
__global__ __launch_bounds__(128)
void gemm_b16_b16(const unsigned short* __restrict__ X,
                  const short* __restrict__ Whi, const short* __restrict__ Wlo,
                  unsigned short* __restrict__ Y, int M) {
  const int wave = threadIdx.x >> 6;
  const int lane = threadIdx.x & 63;
  const int mrow = lane & 15;
  const int quad = lane >> 4;
  const int row0 = blockIdx.x * 64 + wave * 32;

  const bf16x8* WH = (const bf16x8*)Whi;
  const bf16x8* WL = (const bf16x8*)Wlo;

  f32x4 acc[2][8];
#pragma unroll
  for (int mt = 0; mt < 2; ++mt)
#pragma unroll
    for (int t = 0; t < 8; ++t) acc[mt][t] = (f32x4){0.f, 0.f, 0.f, 0.f};

  int rA0 = row0 + mrow;      if (rA0 > M - 1) rA0 = M - 1;
  int rA1 = row0 + 16 + mrow; if (rA1 > M - 1) rA1 = M - 1;
  const bf16x8* xp0 = (const bf16x8*)(X + (size_t)rA0 * CF + quad * 8);
  const bf16x8* xp1 = (const bf16x8*)(X + (size_t)rA1 * CF + quad * 8);

#pragma unroll
  for (int s = 0; s < 4; ++s) {
    bf16x8 A0 = xp0[s * 4];
    bf16x8 A1 = xp1[s * 4];
#pragma unroll
    for (int t = 0; t < 8; ++t) {
      const bf16x8 bh = WH[(s * 8 + t) * 64 + lane];
      const bf16x8 bl = WL[(s * 8 + t) * 64 + lane];
      acc[0][t] = __builtin_amdgcn_mfma_f32_16x16x32_bf16(A0, bh, acc[0][t], 0, 0, 0);
      acc[0][t] = __builtin_amdgcn_mfma_f32_16x16x32_bf16(A0, bl, acc[0][t], 0, 0, 0);
      acc[1][t] = __builtin_amdgcn_mfma_f32_16x16x32_bf16(A1, bh, acc[1][t], 0, 0, 0);
      acc[1][t] = __builtin_amdgcn_mfma_f32_16x16x32_bf16(A1, bl, acc[1][t], 0, 0, 0);
    }
  }

#pragma unroll
  for (int mt = 0; mt < 2; ++mt)
#pragma unroll
    for (int reg = 0; reg < 4; ++reg) {
      const int r = row0 + mt * 16 + quad * 4 + reg;
      if (r < M) {
        unsigned short* yp = Y + (size_t)r * CF + mrow;
#pragma unroll
        for (int t = 0; t < 8; ++t) yp[t * 16] = bf16rne(acc[mt][t][reg]);
      }
    }
}

// --------------------------- scan kernels ----------------------------------
__global__ __launch_bounds__(256)
void scan_block(const int* __restrict__ cnt, int* __restrict__ ptr,
                int* __restrict__ blksum, int n) {
  __shared__ int sdata[256];
  const int t = threadIdx.x;
  const int idx = blockIdx.x * 1024 + t * 4;
  int v[4];
#pragma unroll
  for (int k = 0; k < 4; ++k) v[k] = (idx + k < n) ? cnt[idx + k] : 0;
  int tsum = v[0] + v[1] + v[2] + v[3];
  sdata[t] = tsum;
  __syncthreads();
  for (int off = 1; off < 256; off <<= 1) {
    int x = (t >= off) ? sdata[t - off] : 0;
    __syncthreads();
    sdata[t] += x;
    __syncthreads();
  }
  if (t == 255) blksum[blockIdx.x] = sdata[255];
  int run = sdata[t] - tsum;
#pragma unroll
  for (int k = 0; k < 4; ++k) {
    if (idx + k < n) ptr[idx + k] = run;
    run += v[k];
  }
}

__global__ void scan_sums(int* blksum, int nb) {
  if (threadIdx.x == 0) {
    int run = 0;
    for (int i = 0; i < nb; ++i) { int c = blksum[i]; blksum[i] = run; run += c; }
  }
}

__global__ __launch_bounds__(256)
void scan_add(int* __restrict__ ptr, int* __restrict__ cursor,
              const int* __restrict__ blkoff, int n) {
  const int off = blkoff[blockIdx.x];
  const int base = blockIdx.x * 1024 + threadIdx.x;
#pragma unroll
  for (int k = 0; k < 4; ++k) {
    int i = base + k * 256;
    if (i < n) { int v = ptr[i] + off; ptr[i] = v; cursor[i] = v; }
  }
}

// --------------------- two-level LDS counting-sort CSR build ---------------
__global__ __launch_bounds__(BT)
void bucket_count(const int* __restrict__ rows, int* __restrict__ cnt,
                  int nnz, int nbuk, int chunk) {
  extern __shared__ int lh[];
  const int blk = blockIdx.x, tid = threadIdx.x;
  for (int b = tid; b < nbuk; b += BT) lh[b] = 0;
  __syncthreads();
  const int i0 = blk * chunk;
  const int i1 = min(i0 + chunk, nnz);
  for (int i = i0 + tid; i < i1; i += BT) atomicAdd(&lh[rows[i] >> RB_SHIFT], 1);
  __syncthreads();
  for (int b = tid; b < nbuk; b += BT) cnt[b * NPASSBLK + blk] = lh[b];
  if (blk == 0 && tid == 0) cnt[nbuk * NPASSBLK] = 0;
}

__global__ __launch_bounds__(BT)
void bucket_scatter(const int* __restrict__ rows, const int* __restrict__ cols,
                    const float* __restrict__ vals, const int* __restrict__ S,
                    int2* __restrict__ prT, int nnz, int nbuk, int chunk) {
  extern __shared__ int lcur[];
  const int blk = blockIdx.x, tid = threadIdx.x;
  for (int b = tid; b < nbuk; b += BT) lcur[b] = S[b * NPASSBLK + blk];
  __syncthreads();
  const int i0 = blk * chunk;
  const int i1 = min(i0 + chunk, nnz);
  for (int i = i0 + tid; i < i1; i += BT) {
    const int r = rows[i];
    const int p = atomicAdd(&lcur[r >> RB_SHIFT], 1);
    prT[p] = make_int2(cols[i] | ((r & (RB - 1)) << 26), __float_as_int(vals[i]));
  }
}

__global__ __launch_bounds__(256)
void bucket_to_csr(const int* __restrict__ S, const int2* __restrict__ prT,
                   int2* __restrict__ pr, int* __restrict__ ptr, int n_rows) {
  __shared__ int h[RB + 1];
  __shared__ int cur[RB];
  const int b = blockIdx.x, tid = threadIdx.x;
  const int js = S[b * NPASSBLK];
  const int je = S[(b + 1) * NPASSBLK];
  if (tid <= RB) h[tid] = 0;
  __syncthreads();
  for (int j = js + tid; j < je; j += 256)
    atomicAdd(&h[((unsigned)prT[j].x) >> 26], 1);
  __syncthreads();
  if (tid == 0) {
    int run = js;
    for (int t = 0; t < RB; ++t) { int c = h[t]; h[t] = run; cur[t] = run; run += c; }
    h[RB] = run;   // == je
  }
  __syncthreads();
  if (tid <= RB) {
    const int r = b * RB + tid;
    if (r <= n_rows) ptr[r] = h[tid];
  }
  for (int j = js + tid; j < je; j += 256) {
    const int2 e = prT[j];
    const unsigned cw = (unsigned)e.x;
    const int p = atomicAdd(&cur[cw >> 26], 1);
    pr[p] = make_int2((int)(cw & 0x03FFFFFFu), e.y);
  }
}

// ----------------------------- CSR SpMM (quad-gather) ----------------------
template <int UNR>
__device__ __forceinline__ void seg_accum(const int* __restrict__ ptr,
                                          const int2* __restrict__ pr,
                                          const unsigned* __restrict__ Xq,
                                          int wid, int g, float* acc) {
  int j = ptr[wid];
  const int je = ptr[wid + 1];
  for (; j < je; j += 4 * UNR) {
    int2 p[UNR];
#pragma unroll
    for (int u = 0; u < UNR; ++u) {
      const int jj = j + 4 * u + g;
      p[u] = (jj < je) ? pr[jj] : make_int2(0, 0);
    }
    uint4 d[UNR];
#pragma unroll
    for (int u = 0; u < UNR; ++u)
      d[u] = *(const uint4*)(Xq + (size_t)p[u].x * 64);
#pragma unroll
    for (int u = 0; u < UNR; ++u) {
      const float v = __int_as_float(p[u].y);
      float2 f;
      f = bf2f(d[u].x); acc[0] += v * f.x; acc[1] += v * f.y;
      f = bf2f(d[u].y); acc[2] += v * f.x; acc[3] += v * f.y;
      f = bf2f(d[u].z); acc[4] += v * f.x; acc[5] += v * f.y;
      f = bf2f(d[u].w); acc[6] += v * f.x; acc[7] += v * f.y;
    }
  }
}

template <bool SIG, int UNR>
__global__ __launch_bounds__(256)
void csr_spmm_b16(const int* __restrict__ ptr, const int2* __restrict__ pr,
                  const unsigned* __restrict__ X, unsigned* __restrict__ Y,
                  int n_rows) {
  const int wid = (blockIdx.x << 2) + (threadIdx.x >> 6);
  if (wid >= n_rows) return;
  const int lane = threadIdx.x & 63;
  const int g = lane >> 4;
  const int q = lane & 15;
  float acc[8];
#pragma unroll
  for (int k = 0; k < 8; ++k) acc[k] = 0.f;
  seg_accum<UNR>(ptr, pr, X + q * 4, wid, g, acc);
#pragma unroll
  for (int k = 0; k < 8; ++k) acc[k] += __shfl_xor(acc[k], 16);
#pragma unroll
  for (int k = 0; k < 8; ++k) acc[k] += __shfl_xor(acc[k], 32);
  if (g == 0) {
    if (SIG) {
#pragma unroll
      for (int k = 0; k < 8; ++k) acc[k] = 1.f / (1.f + __expf(-acc[k]));
    }
    uint4 o;
    o.x = (unsigned)bf16rne(acc[0]) | ((unsigned)bf16rne(acc[1]) << 16);
    o.y = (unsigned)bf16rne(acc[2]) | ((unsigned)bf16rne(acc[3]) << 16);
    o.z = (unsigned)bf16rne(acc[4]) | ((unsigned)bf16rne(acc[5]) << 16);
    o.w = (unsigned)bf16rne(acc[6]) | ((unsigned)bf16rne(acc[7]) << 16);
    *(uint4*)(Y + (size_t)wid * 64 + q * 4) = o;
  }
}

// Fused level-2 merge: out[r] = sigmoid( adj-seg(XA) + inc-seg(XB) ), f32 out.
__global__ __launch_bounds__(256)
void csr_spmm2_sig(const int* __restrict__ ptrA, const int2* __restrict__ prA,
                   const unsigned* __restrict__ XA,
                   const int* __restrict__ ptrB, const int2* __restrict__ prB,
                   const unsigned* __restrict__ XB,
                   float* __restrict__ Y, int n_rows) {
  const int wid = (blockIdx.x << 2) + (threadIdx.x >> 6);
  if (wid >= n_rows) return;
  const int lane = threadIdx.x & 63;
  const int g = lane >> 4;
  const int q = lane & 15;
  float acc[8];
#pragma unroll
  for (int k = 0; k < 8; ++k) acc[k] = 0.f;
  seg_accum<4>(ptrA, prA, XA + q * 4, wid, g, acc);
  seg_accum<1>(ptrB, prB, XB + q * 4, wid, g, acc);
#pragma unroll
  for (int k = 0; k < 8; ++k) acc[k] += __shfl_xor(acc[k], 16);
#pragma unroll
  for (int k = 0; k < 8; ++k) acc[k] += __shfl_xor(acc[k], 32);
  if (g == 0) {
#pragma unroll
    for (int k = 0; k < 8; ++k) acc[k] = 1.f / (1.f + __expf(-acc[k]));
    float4* yp = (float4*)(Y + (size_t)wid * CF + q * 8);
    yp[0] = make_float4(acc[0], acc[1], acc[2], acc[3]);
    yp[1] = make_float4(acc[4], acc[5], acc[6], acc[7]);
  }
}

// ---------------------------------------------------------------------------
extern "C" void kernel_launch(void* const* d_in, const int* in_sizes, int n_in,
                              void* d_out, int out_size, void* d_ws, size_t ws_size,
                              hipStream_t stream) {
  const float* x      = (const float*)d_in[0];
  const float* W1_00  = (const float*)d_in[1];
  const float* W1_01  = (const float*)d_in[2];
  const float* W2_00  = (const float*)d_in[3];
  const float* W2_10  = (const float*)d_in[4];
  const int*   adj_rows = (const int*)d_in[5];
  const int*   adj_cols = (const int*)d_in[6];
  const float* adj_vals = (const float*)d_in[7];
  const int*   inc_rows = (const int*)d_in[8];
  const int*   inc_cols = (const int*)d_in[9];
  const float* inc_vals = (const float*)d_in[10];

  const int adj_nnz = in_sizes[5];       // 3,200,000
  const int inc_nnz = in_sizes[8];       // 400,000
  const int NN = in_sizes[0] / CF;       // 100,000 nodes
  const int EN = 200000;                 // edges (problem constant)

  const long long NE = (long long)NN * CF;   // node features
  const long long EE = (long long)EN * CF;   // edge features
  const int PN = ((NN + 2) & ~1);            // padded (8B-align int2 arrays)
  const int PE = ((EN + 2) & ~1);

  // ---- workspace layout ----
  unsigned short* tA = (unsigned short*)d_ws;   // NE bf16 : t2; prT alias at build
  unsigned short* n1 = tA + NE;                 // NE bf16 : sig l1 -> t3
  unsigned short* e1 = n1 + NE;                 // EE bf16 : sig l1 -> t4; cnt/S alias at build
  int*   ptr_a = (int*)(e1 + EE);
  int*   cur_a = ptr_a + PN;                    // (unused, layout stability)
  int2*  pr_a  = (int2*)(cur_a + PN);
  int*   ptr_e = (int*)(pr_a + adj_nnz);
  int*   cur_e = ptr_e + PE;                    // (unused)
  int2*  pr_e  = (int2*)(cur_e + PE);
  int*   ptr_i = (int*)(pr_e + inc_nnz);
  int*   cur_i = ptr_i + PN;                    // (unused)
  int2*  pr_i  = (int2*)(cur_i + PN);
  int*   blks  = (int*)(pr_i + inc_nnz);        // 1024 ints
  short* wp = (short*)(((uintptr_t)(blks + 1024) + 63) & ~(uintptr_t)63);
  short* w00h = wp;            short* w00l = wp + 16384;
  short* w01h = wp + 2*16384;  short* w01l = wp + 3*16384;
  short* w20h = wp + 4*16384;  short* w20l = wp + 5*16384;
  short* w21h = wp + 6*16384;  short* w21l = wp + 7*16384;

  // build-time scratch aliased onto feature buffers (dead until GEMMs):
  // max nS = (200000/64)*256+1 = 800,001 ints (3.2 MB); e1 region is 51 MB.
  int2* prT  = (int2*)tA;        // <= adj_nnz*8 B  (= tA region, spill->n1 safe)
  int*  cntA = (int*)e1;         // <= 800,001 ints
  int*  SA   = cntA + 800064;    // exclusive-scanned offsets (8B-aligned)

  unsigned short* t1 = (unsigned short*)d_out;  // bf16 scratch; dead before final write
  float* outf = (float*)d_out;

  const dim3 blk(256);
  const int gN = (NN + 63) / 64;
  const int gE = (EN + 63) / 64;

  // ---- pack weights (one launch, 4 matrices) ----
  pack_w4<<<32, blk, 0, stream>>>(W1_00, W1_01, W2_00, W2_10, wp);

  // ---- CSR builds via two-level LDS counting sort ----
  auto build = [&](const int* rows, const int* cols, const float* vals,
                   int nnz, int n_rows, int* ptr, int2* pr) {
    const int nbuk  = (n_rows + RB - 1) >> RB_SHIFT;
    const int chunk = (nnz + NPASSBLK - 1) / NPASSBLK;
    const int nS    = nbuk * NPASSBLK + 1;
    const int nbS   = (nS + 1023) / 1024;
    bucket_count<<<NPASSBLK, dim3(BT), nbuk * 4, stream>>>(rows, cntA, nnz, nbuk, chunk);
    scan_block<<<nbS, blk, 0, stream>>>(cntA, SA, blks, nS);
    scan_sums<<<1, 64, 0, stream>>>(blks, nbS);
    scan_add<<<nbS, blk, 0, stream>>>(SA, cntA /*dummy cursor*/, blks, nS);
    bucket_scatter<<<NPASSBLK, dim3(BT), nbuk * 4, stream>>>(rows, cols, vals, SA, prT, nnz, nbuk, chunk);
    bucket_to_csr<<<nbuk, blk, 0, stream>>>(SA, prT, pr, ptr, n_rows);
  };

  build(adj_rows, adj_cols, adj_vals, adj_nnz, NN, ptr_a, pr_a);  // adj by rows
  build(inc_cols, inc_rows, inc_vals, inc_nnz, EN, ptr_e, pr_e);  // B1^T: rows=edges
  build(inc_rows, inc_cols, inc_vals, inc_nnz, NN, ptr_i, pr_i);  // B1: rows=nodes

  // ---- level 1 GEMMs (f32 x -> bf16 out) ----
  gemm_f32_b16<<<gN, dim3(128), 0, stream>>>(x, w00h, w00l, t1, NN);
  gemm_f32_b16<<<gN, dim3(128), 0, stream>>>(x, w01h, w01l, tA, NN);

  // ---- level 1 SpMMs (bf16 quad-gather, fused sigmoid, bf16 out) ----
  csr_spmm_b16<true, 4><<<(NN + 3) / 4, blk, 0, stream>>>(ptr_a, pr_a, (const unsigned*)t1, (unsigned*)n1, NN);
  csr_spmm_b16<true, 1><<<(EN + 3) / 4, blk, 0, stream>>>(ptr_e, pr_e, (const unsigned*)tA, (unsigned*)e1, EN);

  // ---- level 2 GEMMs (bf16 in/out, in-place) ----
  gemm_b16_b16<<<gN, dim3(128), 0, stream>>>(n1, w20h, w20l, n1, NN);
  gemm_b16_b16<<<gE, dim3(128), 0, stream>>>(e1, w21h, w21l, e1, EN);

  // ---- fused level-2 SpMMs + merge sigmoid (f32 out) ----
  csr_spmm2_sig<<<(NN + 3) / 4, blk, 0, stream>>>(ptr_a, pr_a, (const unsigned*)n1,
                                                  ptr_i, pr_i, (const unsigned*)e1, outf, NN);
}

// Round 4
// 739.290 us; speedup vs baseline: 1.3815x; 1.1992x over previous
//
#include <hip/hip_runtime.h>

// HSN layer: out = sigmoid( A0 @ (sig(A0 @ (x W1_00)) W2_00) + B1 @ (sig(B1^T @ (x W1_01)) W2_10) )
// C = 128 fixed. CSR-gather SpMM (no f32 atomics) + MFMA GEMMs.
// Intermediate features in bf16 (256 B/row) to halve gather traffic.
// CSR build: two-level LDS counting sort (no global atomics, clustered writes).
// SpMM: quad-gather (4 lane-groups x 16 lanes, uint4/lane); adj segments UNR=8
//   (32 gathers = 8 KB in flight per wave) + packed f32x2 FMA (v_pk_fma_f32).
// R4: scan_sums was a single-thread loop of up to 782 dependent L2 round-trips
//   per build -- replaced with a 256-thread LDS scan.

#define CF 128
#define RB 64          // rows per bucket (2^RB_SHIFT)
#define RB_SHIFT 6
#define NPASSBLK 256   // blocks (chunks) in count/scatter passes
#define BT 512         // threads per count/scatter block

typedef __attribute__((ext_vector_type(8))) short bf16x8;
typedef __attribute__((ext_vector_type(4))) float f32x4;
typedef __attribute__((ext_vector_type(2))) float f32x2;

// f32 -> bf16 round-to-nearest-even (finite inputs)
__device__ __forceinline__ unsigned short bf16rne(float f) {
  unsigned u = __float_as_uint(f);
  u += 0x7FFFu + ((u >> 16) & 1u);
  return (unsigned short)(u >> 16);
}
// split f32 -> bf16 hi (trunc) + bf16 lo (residual)
__device__ __forceinline__ void splitf(float f, short& h, short& l) {
  unsigned u = __float_as_uint(f);
  h = (short)(u >> 16);
  float fh = __uint_as_float(u & 0xFFFF0000u);
  float r = f - fh;
  l = (short)(__float_as_uint(r) >> 16);
}
// packed bf16 pair -> f32x2 (x = even feature, y = odd)
__device__ __forceinline__ f32x2 bf2v(unsigned u) {
  f32x2 f;
  f.x = __uint_as_float(u << 16);
  f.y = __uint_as_float(u & 0xFFFF0000u);
  return f;
}

// ---------------------------------------------------------------------------
// Pack 4x W[128][128] f32 (row-major [k][n]) into mfma_f32_16x16x32_bf16
// B-fragment order: frag[(s*8+t)*64+lane][j] = W[s*32+(lane>>4)*8+j][t*16+(lane&15)]
// ---------------------------------------------------------------------------
__global__ __launch_bounds__(256)
void pack_w4(const float* __restrict__ W0, const float* __restrict__ W1,
             const float* __restrict__ W2, const float* __restrict__ W3,
             short* __restrict__ wp) {
  const int w = blockIdx.x >> 3;
  const float* W = (w == 0) ? W0 : (w == 1) ? W1 : (w == 2) ? W2 : W3;
  short* hi = wp + (size_t)w * 32768;
  short* lo = hi + 16384;
  const int tid = (blockIdx.x & 7) * 256 + threadIdx.x;   // 0..2047
  const int lane = tid & 63;
  const int t = (tid >> 6) & 7;
  const int s = tid >> 9;
  const int n = t * 16 + (lane & 15);
  const int k0 = s * 32 + ((lane >> 4) << 3);
  short* hp = hi + (size_t)tid * 8;
  short* lp = lo + (size_t)tid * 8;
#pragma unroll
  for (int j = 0; j < 8; ++j) {
    short h, l;
    splitf(W[(size_t)(k0 + j) * CF + n], h, l);
    hp[j] = h;
    lp[j] = l;
  }
}

// ---------------------------------------------------------------------------
// GEMM (f32 in, bf16 out): Y = X @ W, 3-term hi/lo split MFMA.
// ---------------------------------------------------------------------------
__global__ __launch_bounds__(128)
void gemm_f32_b16(const float* __restrict__ X, const short* __restrict__ Whi,
                  const short* __restrict__ Wlo, unsigned short* __restrict__ Y,
                  int M) {
  const int wave = threadIdx.x >> 6;
  const int lane = threadIdx.x & 63;
  const int mrow = lane & 15;
  const int quad = lane >> 4;
  const int row0 = blockIdx.x * 64 + wave * 32;

  const bf16x8* WH = (const bf16x8*)Whi;
  const bf16x8* WL = (const bf16x8*)Wlo;

  f32x4 acc[2][8];
#pragma unroll
  for (int mt = 0; mt < 2; ++mt)
#pragma unroll
    for (int t = 0; t < 8; ++t) acc[mt][t] = (f32x4){0.f, 0.f, 0.f, 0.f};

  int rA0 = row0 + mrow;      if (rA0 > M - 1) rA0 = M - 1;
  int rA1 = row0 + 16 + mrow; if (rA1 > M - 1) rA1 = M - 1;
  const float* xp0 = X + (size_t)rA0 * CF + quad * 8;
  const float* xp1 = X + (size_t)rA1 * CF + quad * 8;

#pragma unroll
  for (int s = 0; s < 4; ++s) {
    bf16x8 Ah[2], Al[2];
    const float* p = xp0 + s * 32;
#pragma unroll
    for (int j = 0; j < 8; ++j) { short h, l; splitf(p[j], h, l); Ah[0][j] = h; Al[0][j] = l; }
    p = xp1 + s * 32;
#pragma unroll
    for (int j = 0; j < 8; ++j) { short h, l; splitf(p[j], h, l); Ah[1][j] = h; Al[1][j] = l; }
#pragma unroll
    for (int t = 0; t < 8; ++t) {
      const bf16x8 bh = WH[(s * 8 + t) * 64 + lane];
      const bf16x8 bl = WL[(s * 8 + t) * 64 + lane];
#pragma unroll
      for (int mt = 0; mt < 2; ++mt) {
        acc[mt][t] = __builtin_amdgcn_mfma_f32_16x16x32_bf16(Ah[mt], bh, acc[mt][t], 0, 0, 0);
        acc[mt][t] = __builtin_amdgcn_mfma_f32_16x16x32_bf16(Al[mt], bh, acc[mt][t], 0, 0, 0);
        acc[mt][t] = __builtin_amdgcn_mfma_f32_16x16x32_bf16(Ah[mt], bl, acc[mt][t], 0, 0, 0);
      }
    }
  }

#pragma unroll
  for (int mt = 0; mt < 2; ++mt)
#pragma unroll
    for (int reg = 0; reg < 4; ++reg) {
      const int r = row0 + mt * 16 + quad * 4 + reg;
      if (r < M) {
        unsigned short* yp = Y + (size_t)r * CF + mrow;
#pragma unroll
        for (int t = 0; t < 8; ++t) yp[t * 16] = bf16rne(acc[mt][t][reg]);
      }
    }
}

// ---------------------------------------------------------------------------
// GEMM (bf16 in, bf16 out): Y = X @ W, 2-term (W split) MFMA. In-place safe.
// ---------------------------------------------------------------------------
__global__ __launch_bounds__(128)
void gemm_b16_b16(const unsigned short* __restrict__ X,
                  const short* __restrict__ Whi, const short* __restrict__ Wlo,
                  unsigned short* __restrict__ Y, int M) {
  const int wave = threadIdx.x >> 6;
  const int lane = threadIdx.x & 63;
  const int mrow = lane & 15;
  const int quad = lane >> 4;
  const int row0 = blockIdx.x * 64 + wave * 32;

  const bf16x8* WH = (const bf16x8*)Whi;
  const bf16x8* WL = (const bf16x8*)Wlo;

  f32x4 acc[2][8];
#pragma unroll
  for (int mt = 0; mt < 2; ++mt)
#pragma unroll
    for (int t = 0; t < 8; ++t) acc[mt][t] = (f32x4){0.f, 0.f, 0.f, 0.f};

  int rA0 = row0 + mrow;      if (rA0 > M - 1) rA0 = M - 1;
  int rA1 = row0 + 16 + mrow; if (rA1 > M - 1) rA1 = M - 1;
  const bf16x8* xp0 = (const bf16x8*)(X + (size_t)rA0 * CF + quad * 8);
  const bf16x8* xp1 = (const bf16x8*)(X + (size_t)rA1 * CF + quad * 8);

#pragma unroll
  for (int s = 0; s < 4; ++s) {
    bf16x8 A0 = xp0[s * 4];
    bf16x8 A1 = xp1[s * 4];
#pragma unroll
    for (int t = 0; t < 8; ++t) {
      const bf16x8 bh = WH[(s * 8 + t) * 64 + lane];
      const bf16x8 bl = WL[(s * 8 + t) * 64 + lane];
      acc[0][t] = __builtin_amdgcn_mfma_f32_16x16x32_bf16(A0, bh, acc[0][t], 0, 0, 0);
      acc[0][t] = __builtin_amdgcn_mfma_f32_16x16x32_bf16(A0, bl, acc[0][t], 0, 0, 0);
      acc[1][t] = __builtin_amdgcn_mfma_f32_16x16x32_bf16(A1, bh, acc[1][t], 0, 0, 0);
      acc[1][t] = __builtin_amdgcn_mfma_f32_16x16x32_bf16(A1, bl, acc[1][t], 0, 0, 0);
    }
  }

#pragma unroll
  for (int mt = 0; mt < 2; ++mt)
#pragma unroll
    for (int reg = 0; reg < 4; ++reg) {
      const int r = row0 + mt * 16 + quad * 4 + reg;
      if (r < M) {
        unsigned short* yp = Y + (size_t)r * CF + mrow;
#pragma unroll
        for (int t = 0; t < 8; ++t) yp[t * 16] = bf16rne(acc[mt][t][reg]);
      }
    }
}

// --------------------------- scan kernels ----------------------------------
__global__ __launch_bounds__(256)
void scan_block(const int* __restrict__ cnt, int* __restrict__ ptr,
                int* __restrict__ blksum, int n) {
  __shared__ int sdata[256];
  const int t = threadIdx.x;
  const int idx = blockIdx.x * 1024 + t * 4;
  int v[4];
#pragma unroll
  for (int k = 0; k < 4; ++k) v[k] = (idx + k < n) ? cnt[idx + k] : 0;
  int tsum = v[0] + v[1] + v[2] + v[3];
  sdata[t] = tsum;
  __syncthreads();
  for (int off = 1; off < 256; off <<= 1) {
    int x = (t >= off) ? sdata[t - off] : 0;
    __syncthreads();
    sdata[t] += x;
    __syncthreads();
  }
  if (t == 255) blksum[blockIdx.x] = sdata[255];
  int run = sdata[t] - tsum;
#pragma unroll
  for (int k = 0; k < 4; ++k) {
    if (idx + k < n) ptr[idx + k] = run;
    run += v[k];
  }
}

// exclusive scan of up to 1024 block sums, single 256-thread block (was a
// serial 1-thread loop of nb dependent L2 round-trips).
__global__ __launch_bounds__(256)
void scan_sums(int* __restrict__ blksum, int nb) {
  __shared__ int sdata[256];
  const int t = threadIdx.x;
  const int idx = t * 4;
  int v[4];
#pragma unroll
  for (int k = 0; k < 4; ++k) v[k] = (idx + k < nb) ? blksum[idx + k] : 0;
  int tsum = v[0] + v[1] + v[2] + v[3];
  sdata[t] = tsum;
  __syncthreads();
  for (int off = 1; off < 256; off <<= 1) {
    int x = (t >= off) ? sdata[t - off] : 0;
    __syncthreads();
    sdata[t] += x;
    __syncthreads();
  }
  int run = sdata[t] - tsum;
#pragma unroll
  for (int k = 0; k < 4; ++k) {
    if (idx + k < nb) blksum[idx + k] = run;
    run += v[k];
  }
}

__global__ __launch_bounds__(256)
void scan_add(int* __restrict__ ptr, int* __restrict__ cursor,
              const int* __restrict__ blkoff, int n) {
  const int off = blkoff[blockIdx.x];
  const int base = blockIdx.x * 1024 + threadIdx.x;
#pragma unroll
  for (int k = 0; k < 4; ++k) {
    int i = base + k * 256;
    if (i < n) { int v = ptr[i] + off; ptr[i] = v; cursor[i] = v; }
  }
}

// --------------------- two-level LDS counting-sort CSR build ---------------
__global__ __launch_bounds__(BT)
void bucket_count(const int* __restrict__ rows, int* __restrict__ cnt,
                  int nnz, int nbuk, int chunk) {
  extern __shared__ int lh[];
  const int blk = blockIdx.x, tid = threadIdx.x;
  for (int b = tid; b < nbuk; b += BT) lh[b] = 0;
  __syncthreads();
  const int i0 = blk * chunk;
  const int i1 = min(i0 + chunk, nnz);
  for (int i = i0 + tid; i < i1; i += BT) atomicAdd(&lh[rows[i] >> RB_SHIFT], 1);
  __syncthreads();
  for (int b = tid; b < nbuk; b += BT) cnt[b * NPASSBLK + blk] = lh[b];
  if (blk == 0 && tid == 0) cnt[nbuk * NPASSBLK] = 0;
}

__global__ __launch_bounds__(BT)
void bucket_scatter(const int* __restrict__ rows, const int* __restrict__ cols,
                    const float* __restrict__ vals, const int* __restrict__ S,
                    int2* __restrict__ prT, int nnz, int nbuk, int chunk) {
  extern __shared__ int lcur[];
  const int blk = blockIdx.x, tid = threadIdx.x;
  for (int b = tid; b < nbuk; b += BT) lcur[b] = S[b * NPASSBLK + blk];
  __syncthreads();
  const int i0 = blk * chunk;
  const int i1 = min(i0 + chunk, nnz);
  for (int i = i0 + tid; i < i1; i += BT) {
    const int r = rows[i];
    const int p = atomicAdd(&lcur[r >> RB_SHIFT], 1);
    prT[p] = make_int2(cols[i] | ((r & (RB - 1)) << 26), __float_as_int(vals[i]));
  }
}

__global__ __launch_bounds__(256)
void bucket_to_csr(const int* __restrict__ S, const int2* __restrict__ prT,
                   int2* __restrict__ pr, int* __restrict__ ptr, int n_rows) {
  __shared__ int h[RB + 1];
  __shared__ int cur[RB];
  const int b = blockIdx.x, tid = threadIdx.x;
  const int js = S[b * NPASSBLK];
  const int je = S[(b + 1) * NPASSBLK];
  if (tid <= RB) h[tid] = 0;
  __syncthreads();
  for (int j = js + tid; j < je; j += 256)
    atomicAdd(&h[((unsigned)prT[j].x) >> 26], 1);
  __syncthreads();
  if (tid == 0) {
    int run = js;
    for (int t = 0; t < RB; ++t) { int c = h[t]; h[t] = run; cur[t] = run; run += c; }
    h[RB] = run;   // == je
  }
  __syncthreads();
  if (tid <= RB) {
    const int r = b * RB + tid;
    if (r <= n_rows) ptr[r] = h[tid];
  }
  for (int j = js + tid; j < je; j += 256) {
    const int2 e = prT[j];
    const unsigned cw = (unsigned)e.x;
    const int p = atomicAdd(&cur[cw >> 26], 1);
    pr[p] = make_int2((int)(cw & 0x03FFFFFFu), e.y);
  }
}

// ----------------------------- CSR SpMM (quad-gather) ----------------------
// Wave = 4 groups x 16 lanes; group g handles nnz j+g; lane q loads uint4
// (8 features). UNR iterations' pr loads issue before gathers -> UNR KB in
// flight per wave. Accumulate via f32x2 fma (-> v_pk_fma_f32). Tail masked
// to (row 0, v=0).
template <int UNR>
__device__ __forceinline__ void seg_accum(const int* __restrict__ ptr,
                                          const int2* __restrict__ pr,
                                          const unsigned* __restrict__ Xq,
                                          int wid, int g, f32x2* acc) {
  int j = ptr[wid];
  const int je = ptr[wid + 1];
  for (; j < je; j += 4 * UNR) {
    int2 p[UNR];
#pragma unroll
    for (int u = 0; u < UNR; ++u) {
      const int jj = j + 4 * u + g;
      p[u] = (jj < je) ? pr[jj] : make_int2(0, 0);
    }
    uint4 d[UNR];
#pragma unroll
    for (int u = 0; u < UNR; ++u)
      d[u] = *(const uint4*)(Xq + (size_t)p[u].x * 64);
#pragma unroll
    for (int u = 0; u < UNR; ++u) {
      const float v = __int_as_float(p[u].y);
      const f32x2 vv = {v, v};
      acc[0] = __builtin_elementwise_fma(vv, bf2v(d[u].x), acc[0]);
      acc[1] = __builtin_elementwise_fma(vv, bf2v(d[u].y), acc[1]);
      acc[2] = __builtin_elementwise_fma(vv, bf2v(d[u].z), acc[2]);
      acc[3] = __builtin_elementwise_fma(vv, bf2v(d[u].w), acc[3]);
    }
  }
}

template <bool SIG, int UNR>
__global__ __launch_bounds__(256)
void csr_spmm_b16(const int* __restrict__ ptr, const int2* __restrict__ pr,
                  const unsigned* __restrict__ X, unsigned* __restrict__ Y,
                  int n_rows) {
  const int wid = (blockIdx.x << 2) + (threadIdx.x >> 6);
  if (wid >= n_rows) return;
  const int lane = threadIdx.x & 63;
  const int g = lane >> 4;
  const int q = lane & 15;
  f32x2 acc[4];
#pragma unroll
  for (int k = 0; k < 4; ++k) acc[k] = (f32x2){0.f, 0.f};
  seg_accum<UNR>(ptr, pr, X + q * 4, wid, g, acc);
#pragma unroll
  for (int k = 0; k < 4; ++k) {
    acc[k].x += __shfl_xor(acc[k].x, 16);
    acc[k].y += __shfl_xor(acc[k].y, 16);
    acc[k].x += __shfl_xor(acc[k].x, 32);
    acc[k].y += __shfl_xor(acc[k].y, 32);
  }
  if (g == 0) {
    if (SIG) {
#pragma unroll
      for (int k = 0; k < 4; ++k) {
        acc[k].x = 1.f / (1.f + __expf(-acc[k].x));
        acc[k].y = 1.f / (1.f + __expf(-acc[k].y));
      }
    }
    uint4 o;
    o.x = (unsigned)bf16rne(acc[0].x) | ((unsigned)bf16rne(acc[0].y) << 16);
    o.y = (unsigned)bf16rne(acc[1].x) | ((unsigned)bf16rne(acc[1].y) << 16);
    o.z = (unsigned)bf16rne(acc[2].x) | ((unsigned)bf16rne(acc[2].y) << 16);
    o.w = (unsigned)bf16rne(acc[3].x) | ((unsigned)bf16rne(acc[3].y) << 16);
    *(uint4*)(Y + (size_t)wid * 64 + q * 4) = o;
  }
}

// Fused level-2 merge: out[r] = sigmoid( adj-seg(XA) + inc-seg(XB) ), f32 out.
__global__ __launch_bounds__(256)
void csr_spmm2_sig(const int* __restrict__ ptrA, const int2* __restrict__ prA,
                   const unsigned* __restrict__ XA,
                   const int* __restrict__ ptrB, const int2* __restrict__ prB,
                   const unsigned* __restrict__ XB,
                   float* __restrict__ Y, int n_rows) {
  const int wid = (blockIdx.x << 2) + (threadIdx.x >> 6);
  if (wid >= n_rows) return;
  const int lane = threadIdx.x & 63;
  const int g = lane >> 4;
  const int q = lane & 15;
  f32x2 acc[4];
#pragma unroll
  for (int k = 0; k < 4; ++k) acc[k] = (f32x2){0.f, 0.f};
  seg_accum<8>(ptrA, prA, XA + q * 4, wid, g, acc);
  seg_accum<1>(ptrB, prB, XB + q * 4, wid, g, acc);
#pragma unroll
  for (int k = 0; k < 4; ++k) {
    acc[k].x += __shfl_xor(acc[k].x, 16);
    acc[k].y += __shfl_xor(acc[k].y, 16);
    acc[k].x += __shfl_xor(acc[k].x, 32);
    acc[k].y += __shfl_xor(acc[k].y, 32);
  }
  if (g == 0) {
#pragma unroll
    for (int k = 0; k < 4; ++k) {
      acc[k].x = 1.f / (1.f + __expf(-acc[k].x));
      acc[k].y = 1.f / (1.f + __expf(-acc[k].y));
    }
    float4* yp = (float4*)(Y + (size_t)wid * CF + q * 8);
    yp[0] = make_float4(acc[0].x, acc[0].y, acc[1].x, acc[1].y);
    yp[1] = make_float4(acc[2].x, acc[2].y, acc[3].x, acc[3].y);
  }
}

// ---------------------------------------------------------------------------
extern "C" void kernel_launch(void* const* d_in, const int* in_sizes, int n_in,
                              void* d_out, int out_size, void* d_ws, size_t ws_size,
                              hipStream_t stream) {
  const float* x      = (const float*)d_in[0];
  const float* W1_00  = (const float*)d_in[1];
  const float* W1_01  = (const float*)d_in[2];
  const float* W2_00  = (const float*)d_in[3];
  const float* W2_10  = (const float*)d_in[4];
  const int*   adj_rows = (const int*)d_in[5];
  const int*   adj_cols = (const int*)d_in[6];
  const float* adj_vals = (const float*)d_in[7];
  const int*   inc_rows = (const int*)d_in[8];
  const int*   inc_cols = (const int*)d_in[9];
  const float* inc_vals = (const float*)d_in[10];

  const int adj_nnz = in_sizes[5];       // 3,200,000
  const int inc_nnz = in_sizes[8];       // 400,000
  const int NN = in_sizes[0] / CF;       // 100,000 nodes
  const int EN = 200000;                 // edges (problem constant)

  const long long NE = (long long)NN * CF;   // node features
  const long long EE = (long long)EN * CF;   // edge features
  const int PN = ((NN + 2) & ~1);            // padded (8B-align int2 arrays)
  const int PE = ((EN + 2) & ~1);

  // ---- workspace layout ----
  unsigned short* tA = (unsigned short*)d_ws;   // NE bf16 : t2; prT alias at build
  unsigned short* n1 = tA + NE;                 // NE bf16 : sig l1 -> t3
  unsigned short* e1 = n1 + NE;                 // EE bf16 : sig l1 -> t4; cnt/S alias at build
  int*   ptr_a = (int*)(e1 + EE);
  int*   cur_a = ptr_a + PN;                    // (unused, layout stability)
  int2*  pr_a  = (int2*)(cur_a + PN);
  int*   ptr_e = (int*)(pr_a + adj_nnz);
  int*   cur_e = ptr_e + PE;                    // (unused)
  int2*  pr_e  = (int2*)(cur_e + PE);
  int*   ptr_i = (int*)(pr_e + inc_nnz);
  int*   cur_i = ptr_i + PN;                    // (unused)
  int2*  pr_i  = (int2*)(cur_i + PN);
  int*   blks  = (int*)(pr_i + inc_nnz);        // 1024 ints
  short* wp = (short*)(((uintptr_t)(blks + 1024) + 63) & ~(uintptr_t)63);
  short* w00h = wp;            short* w00l = wp + 16384;
  short* w01h = wp + 2*16384;  short* w01l = wp + 3*16384;
  short* w20h = wp + 4*16384;  short* w20l = wp + 5*16384;
  short* w21h = wp + 6*16384;  short* w21l = wp + 7*16384;

  // build-time scratch aliased onto feature buffers (dead until GEMMs):
  // max nS = (200000/64)*256+1 = 800,001 ints (3.2 MB); e1 region is 51 MB.
  int2* prT  = (int2*)tA;        // <= adj_nnz*8 B  (= tA region, spill->n1 safe)
  int*  cntA = (int*)e1;         // <= 800,001 ints
  int*  SA   = cntA + 800064;    // exclusive-scanned offsets (8B-aligned)

  unsigned short* t1 = (unsigned short*)d_out;  // bf16 scratch; dead before final write
  float* outf = (float*)d_out;

  const dim3 blk(256);
  const int gN = (NN + 63) / 64;
  const int gE = (EN + 63) / 64;

  // ---- pack weights (one launch, 4 matrices) ----
  pack_w4<<<32, blk, 0, stream>>>(W1_00, W1_01, W2_00, W2_10, wp);

  // ---- CSR builds via two-level LDS counting sort ----
  auto build = [&](const int* rows, const int* cols, const float* vals,
                   int nnz, int n_rows, int* ptr, int2* pr) {
    const int nbuk  = (n_rows + RB - 1) >> RB_SHIFT;
    const int chunk = (nnz + NPASSBLK - 1) / NPASSBLK;
    const int nS    = nbuk * NPASSBLK + 1;
    const int nbS   = (nS + 1023) / 1024;
    bucket_count<<<NPASSBLK, dim3(BT), nbuk * 4, stream>>>(rows, cntA, nnz, nbuk, chunk);
    scan_block<<<nbS, blk, 0, stream>>>(cntA, SA, blks, nS);
    scan_sums<<<1, blk, 0, stream>>>(blks, nbS);
    scan_add<<<nbS, blk, 0, stream>>>(SA, cntA /*dummy cursor*/, blks, nS);
    bucket_scatter<<<NPASSBLK, dim3(BT), nbuk * 4, stream>>>(rows, cols, vals, SA, prT, nnz, nbuk, chunk);
    bucket_to_csr<<<nbuk, blk, 0, stream>>>(SA, prT, pr, ptr, n_rows);
  };

  build(adj_rows, adj_cols, adj_vals, adj_nnz, NN, ptr_a, pr_a);  // adj by rows
  build(inc_cols, inc_rows, inc_vals, inc_nnz, EN, ptr_e, pr_e);  // B1^T: rows=edges
  build(inc_rows, inc_cols, inc_vals, inc_nnz, NN, ptr_i, pr_i);  // B1: rows=nodes

  // ---- level 1 GEMMs (f32 x -> bf16 out) ----
  gemm_f32_b16<<<gN, dim3(128), 0, stream>>>(x, w00h, w00l, t1, NN);
  gemm_f32_b16<<<gN, dim3(128), 0, stream>>>(x, w01h, w01l, tA, NN);

  // ---- level 1 SpMMs (bf16 quad-gather, fused sigmoid, bf16 out) ----
  csr_spmm_b16<true, 8><<<(NN + 3) / 4, blk, 0, stream>>>(ptr_a, pr_a, (const unsigned*)t1, (unsigned*)n1, NN);
  csr_spmm_b16<true, 1><<<(EN + 3) / 4, blk, 0, stream>>>(ptr_e, pr_e, (const unsigned*)tA, (unsigned*)e1, EN);

  // ---- level 2 GEMMs (bf16 in/out, in-place) ----
  gemm_b16_b16<<<gN, dim3(128), 0, stream>>>(n1, w20h, w20l, n1, NN);
  gemm_b16_b16<<<gE, dim3(128), 0, stream>>>(e1, w21h, w21l, e1, EN);

  // ---- fused level-2 SpMMs + merge sigmoid (f32 out) ----
  csr_spmm2_sig<<<(NN + 3) / 4, blk, 0, stream>>>(ptr_a, pr_a, (const unsigned*)n1,
                                                  ptr_i, pr_i, (const unsigned*)e1, outf, NN);
}

// Round 5
// 666.042 us; speedup vs baseline: 1.5334x; 1.1100x over previous
//
#include <hip/hip_runtime.h>

// HSN layer: out = sigmoid( A0 @ (sig(A0 @ (x W1_00)) W2_00) + B1 @ (sig(B1^T @ (x W1_01)) W2_10) )
// C = 128 fixed. CSR-gather SpMM (no f32 atomics) + MFMA GEMMs.
// Intermediate features bf16. CSR build: two-level LDS counting sort.
// R5: dispatch-count reduction 26 -> 11. All three CSR builds fused into one
//   count/scan/scatter/to_csr chain (concatenated bucket domain); L1 GEMM pair,
//   L1 SpMM pair, L2 GEMM pair fused via block-range dispatch. Adj SpMM UNR
//   reverted 8->4 (R4 showed VGPR 36 cut occupancy 78->68%, net loss).

#define CF 128
#define RB 64          // rows per bucket (2^RB_SHIFT)
#define RB_SHIFT 6
#define NPASSBLK 256   // blocks (chunks) per matrix in count/scatter passes
#define BT 512         // threads per count/scatter block

typedef __attribute__((ext_vector_type(8))) short bf16x8;
typedef __attribute__((ext_vector_type(4))) float f32x4;
typedef __attribute__((ext_vector_type(2))) float f32x2;

__device__ __forceinline__ unsigned short bf16rne(float f) {
  unsigned u = __float_as_uint(f);
  u += 0x7FFFu + ((u >> 16) & 1u);
  return (unsigned short)(u >> 16);
}
__device__ __forceinline__ void splitf(float f, short& h, short& l) {
  unsigned u = __float_as_uint(f);
  h = (short)(u >> 16);
  float fh = __uint_as_float(u & 0xFFFF0000u);
  float r = f - fh;
  l = (short)(__float_as_uint(r) >> 16);
}
__device__ __forceinline__ f32x2 bf2v(unsigned u) {
  f32x2 f;
  f.x = __uint_as_float(u << 16);
  f.y = __uint_as_float(u & 0xFFFF0000u);
  return f;
}

// ---------------------------------------------------------------------------
// Pack 4x W[128][128] f32 into mfma_f32_16x16x32_bf16 B-fragment order:
// frag[(s*8+t)*64+lane][j] = W[s*32+(lane>>4)*8+j][t*16+(lane&15)]
// ---------------------------------------------------------------------------
__global__ __launch_bounds__(256)
void pack_w4(const float* __restrict__ W0, const float* __restrict__ W1,
             const float* __restrict__ W2, const float* __restrict__ W3,
             short* __restrict__ wp) {
  const int w = blockIdx.x >> 3;
  const float* W = (w == 0) ? W0 : (w == 1) ? W1 : (w == 2) ? W2 : W3;
  short* hi = wp + (size_t)w * 32768;
  short* lo = hi + 16384;
  const int tid = (blockIdx.x & 7) * 256 + threadIdx.x;   // 0..2047
  const int lane = tid & 63;
  const int t = (tid >> 6) & 7;
  const int s = tid >> 9;
  const int n = t * 16 + (lane & 15);
  const int k0 = s * 32 + ((lane >> 4) << 3);
  short* hp = hi + (size_t)tid * 8;
  short* lp = lo + (size_t)tid * 8;
#pragma unroll
  for (int j = 0; j < 8; ++j) {
    short h, l;
    splitf(W[(size_t)(k0 + j) * CF + n], h, l);
    hp[j] = h;
    lp[j] = l;
  }
}

// ---------------------------------------------------------------------------
// GEMM bodies (device functions, called from fused range-dispatch kernels)
// ---------------------------------------------------------------------------
__device__ __forceinline__ void gemm_f32_body(const float* __restrict__ X,
                                              const short* __restrict__ Whi,
                                              const short* __restrict__ Wlo,
                                              unsigned short* __restrict__ Y,
                                              int M, int blk) {
  const int wave = threadIdx.x >> 6;
  const int lane = threadIdx.x & 63;
  const int mrow = lane & 15;
  const int quad = lane >> 4;
  const int row0 = blk * 64 + wave * 32;

  const bf16x8* WH = (const bf16x8*)Whi;
  const bf16x8* WL = (const bf16x8*)Wlo;

  f32x4 acc[2][8];
#pragma unroll
  for (int mt = 0; mt < 2; ++mt)
#pragma unroll
    for (int t = 0; t < 8; ++t) acc[mt][t] = (f32x4){0.f, 0.f, 0.f, 0.f};

  int rA0 = row0 + mrow;      if (rA0 > M - 1) rA0 = M - 1;
  int rA1 = row0 + 16 + mrow; if (rA1 > M - 1) rA1 = M - 1;
  const float* xp0 = X + (size_t)rA0 * CF + quad * 8;
  const float* xp1 = X + (size_t)rA1 * CF + quad * 8;

#pragma unroll
  for (int s = 0; s < 4; ++s) {
    bf16x8 Ah[2], Al[2];
    const float* p = xp0 + s * 32;
#pragma unroll
    for (int j = 0; j < 8; ++j) { short h, l; splitf(p[j], h, l); Ah[0][j] = h; Al[0][j] = l; }
    p = xp1 + s * 32;
#pragma unroll
    for (int j = 0; j < 8; ++j) { short h, l; splitf(p[j], h, l); Ah[1][j] = h; Al[1][j] = l; }
#pragma unroll
    for (int t = 0; t < 8; ++t) {
      const bf16x8 bh = WH[(s * 8 + t) * 64 + lane];
      const bf16x8 bl = WL[(s * 8 + t) * 64 + lane];
#pragma unroll
      for (int mt = 0; mt < 2; ++mt) {
        acc[mt][t] = __builtin_amdgcn_mfma_f32_16x16x32_bf16(Ah[mt], bh, acc[mt][t], 0, 0, 0);
        acc[mt][t] = __builtin_amdgcn_mfma_f32_16x16x32_bf16(Al[mt], bh, acc[mt][t], 0, 0, 0);
        acc[mt][t] = __builtin_amdgcn_mfma_f32_16x16x32_bf16(Ah[mt], bl, acc[mt][t], 0, 0, 0);
      }
    }
  }

#pragma unroll
  for (int mt = 0; mt < 2; ++mt)
#pragma unroll
    for (int reg = 0; reg < 4; ++reg) {
      const int r = row0 + mt * 16 + quad * 4 + reg;
      if (r < M) {
        unsigned short* yp = Y + (size_t)r * CF + mrow;
#pragma unroll
        for (int t = 0; t < 8; ++t) yp[t * 16] = bf16rne(acc[mt][t][reg]);
      }
    }
}

__device__ __forceinline__ void gemm_b16_body(const unsigned short* __restrict__ X,
                                              const short* __restrict__ Whi,
                                              const short* __restrict__ Wlo,
                                              unsigned short* __restrict__ Y,
                                              int M, int blk) {
  const int wave = threadIdx.x >> 6;
  const int lane = threadIdx.x & 63;
  const int mrow = lane & 15;
  const int quad = lane >> 4;
  const int row0 = blk * 64 + wave * 32;

  const bf16x8* WH = (const bf16x8*)Whi;
  const bf16x8* WL = (const bf16x8*)Wlo;

  f32x4 acc[2][8];
#pragma unroll
  for (int mt = 0; mt < 2; ++mt)
#pragma unroll
    for (int t = 0; t < 8; ++t) acc[mt][t] = (f32x4){0.f, 0.f, 0.f, 0.f};

  int rA0 = row0 + mrow;      if (rA0 > M - 1) rA0 = M - 1;
  int rA1 = row0 + 16 + mrow; if (rA1 > M - 1) rA1 = M - 1;
  const bf16x8* xp0 = (const bf16x8*)(X + (size_t)rA0 * CF + quad * 8);
  const bf16x8* xp1 = (const bf16x8*)(X + (size_t)rA1 * CF + quad * 8);

#pragma unroll
  for (int s = 0; s < 4; ++s) {
    bf16x8 A0 = xp0[s * 4];
    bf16x8 A1 = xp1[s * 4];
#pragma unroll
    for (int t = 0; t < 8; ++t) {
      const bf16x8 bh = WH[(s * 8 + t) * 64 + lane];
      const bf16x8 bl = WL[(s * 8 + t) * 64 + lane];
      acc[0][t] = __builtin_amdgcn_mfma_f32_16x16x32_bf16(A0, bh, acc[0][t], 0, 0, 0);
      acc[0][t] = __builtin_amdgcn_mfma_f32_16x16x32_bf16(A0, bl, acc[0][t], 0, 0, 0);
      acc[1][t] = __builtin_amdgcn_mfma_f32_16x16x32_bf16(A1, bh, acc[1][t], 0, 0, 0);
      acc[1][t] = __builtin_amdgcn_mfma_f32_16x16x32_bf16(A1, bl, acc[1][t], 0, 0, 0);
    }
  }

#pragma unroll
  for (int mt = 0; mt < 2; ++mt)
#pragma unroll
    for (int reg = 0; reg < 4; ++reg) {
      const int r = row0 + mt * 16 + quad * 4 + reg;
      if (r < M) {
        unsigned short* yp = Y + (size_t)r * CF + mrow;
#pragma unroll
        for (int t = 0; t < 8; ++t) yp[t * 16] = bf16rne(acc[mt][t][reg]);
      }
    }
}

// fused L1: blocks [0,g) -> Y0 = X@W00 ; [g,2g) -> Y1 = X@W01 (same X, M)
__global__ __launch_bounds__(128)
void gemm_f32_l1(const float* __restrict__ X,
                 const short* __restrict__ w00, const short* __restrict__ w01,
                 unsigned short* __restrict__ Y0, unsigned short* __restrict__ Y1,
                 int M, int g) {
  if ((int)blockIdx.x < g)
    gemm_f32_body(X, w00, w00 + 16384, Y0, M, blockIdx.x);
  else
    gemm_f32_body(X, w01, w01 + 16384, Y1, M, blockIdx.x - g);
}

// fused L2: blocks [0,gN) -> n1 = n1@W20 ; [gN,gN+gE) -> e1 = e1@W21
__global__ __launch_bounds__(128)
void gemm_b16_l2(unsigned short* __restrict__ n1, const short* __restrict__ w20,
                 unsigned short* __restrict__ e1, const short* __restrict__ w21,
                 int MN, int ME, int gN) {
  if ((int)blockIdx.x < gN)
    gemm_b16_body(n1, w20, w20 + 16384, n1, MN, blockIdx.x);
  else
    gemm_b16_body(e1, w21, w21 + 16384, e1, ME, blockIdx.x - gN);
}

// --------------------------- scan kernels ----------------------------------
__global__ __launch_bounds__(256)
void scan_block(const int* __restrict__ cnt, int* __restrict__ ptr,
                int* __restrict__ blksum, int n) {
  __shared__ int sdata[256];
  const int t = threadIdx.x;
  const int idx = blockIdx.x * 1024 + t * 4;
  int v[4];
#pragma unroll
  for (int k = 0; k < 4; ++k) v[k] = (idx + k < n) ? cnt[idx + k] : 0;
  int tsum = v[0] + v[1] + v[2] + v[3];
  sdata[t] = tsum;
  __syncthreads();
  for (int off = 1; off < 256; off <<= 1) {
    int x = (t >= off) ? sdata[t - off] : 0;
    __syncthreads();
    sdata[t] += x;
    __syncthreads();
  }
  if (t == 255) blksum[blockIdx.x] = sdata[255];
  int run = sdata[t] - tsum;
#pragma unroll
  for (int k = 0; k < 4; ++k) {
    if (idx + k < n) ptr[idx + k] = run;
    run += v[k];
  }
}

// exclusive scan of up to 2048 block sums, one 256-thread block.
__global__ __launch_bounds__(256)
void scan_sums(int* __restrict__ blksum, int nb) {
  __shared__ int sdata[256];
  const int t = threadIdx.x;
  const int idx = t * 8;
  int v[8];
#pragma unroll
  for (int k = 0; k < 8; ++k) v[k] = (idx + k < nb) ? blksum[idx + k] : 0;
  int tsum = 0;
#pragma unroll
  for (int k = 0; k < 8; ++k) tsum += v[k];
  sdata[t] = tsum;
  __syncthreads();
  for (int off = 1; off < 256; off <<= 1) {
    int x = (t >= off) ? sdata[t - off] : 0;
    __syncthreads();
    sdata[t] += x;
    __syncthreads();
  }
  int run = sdata[t] - tsum;
#pragma unroll
  for (int k = 0; k < 8; ++k) {
    if (idx + k < nb) blksum[idx + k] = run;
    run += v[k];
  }
}

__global__ __launch_bounds__(256)
void scan_add(int* __restrict__ ptr, const int* __restrict__ blkoff, int n) {
  const int off = blkoff[blockIdx.x];
  const int base = blockIdx.x * 1024 + threadIdx.x;
#pragma unroll
  for (int k = 0; k < 4; ++k) {
    int i = base + k * 256;
    if (i < n) ptr[i] += off;
  }
}

// ------------- fused three-matrix two-level counting-sort build ------------
// Concatenated bucket domain: adj buckets [0,nb0), incT [nb0,nb0+nb1),
// inc [nb0+nb1,totbuk). cnt/S layout: cell[(bukbase+b)*NPASSBLK + blk].
__global__ __launch_bounds__(BT)
void bucket_count3(const int* __restrict__ r0, const int* __restrict__ r1,
                   const int* __restrict__ r2, int* __restrict__ cnt,
                   int nnz0, int nnz1, int nnz2, int nb0, int nb1, int nb2) {
  extern __shared__ int lh[];
  const int m = blockIdx.x / NPASSBLK;
  const int blk = blockIdx.x % NPASSBLK;
  const int tid = threadIdx.x;
  const int* rows = (m == 0) ? r0 : (m == 1) ? r1 : r2;
  const int nnz  = (m == 0) ? nnz0 : (m == 1) ? nnz1 : nnz2;
  const int nbuk = (m == 0) ? nb0 : (m == 1) ? nb1 : nb2;
  const int bukbase = (m == 0) ? 0 : (m == 1) ? nb0 : nb0 + nb1;
  const int chunk = (nnz + NPASSBLK - 1) / NPASSBLK;
  for (int b = tid; b < nbuk; b += BT) lh[b] = 0;
  __syncthreads();
  const int i0 = blk * chunk;
  const int i1 = min(i0 + chunk, nnz);
  for (int i = i0 + tid; i < i1; i += BT) atomicAdd(&lh[rows[i] >> RB_SHIFT], 1);
  __syncthreads();
  for (int b = tid; b < nbuk; b += BT)
    cnt[(size_t)(bukbase + b) * NPASSBLK + blk] = lh[b];
  if (m == 0 && blk == 0 && tid == 0)
    cnt[(size_t)(nb0 + nb1 + nb2) * NPASSBLK] = 0;
}

__global__ __launch_bounds__(BT)
void bucket_scatter3(const int* __restrict__ r0, const int* __restrict__ c0,
                     const float* __restrict__ v0,
                     const int* __restrict__ r1, const int* __restrict__ c1,
                     const float* __restrict__ v1,
                     const int* __restrict__ r2, const int* __restrict__ c2,
                     const float* __restrict__ v2,
                     const int* __restrict__ S, int2* __restrict__ prT,
                     int nnz0, int nnz1, int nnz2, int nb0, int nb1, int nb2) {
  extern __shared__ int lcur[];
  const int m = blockIdx.x / NPASSBLK;
  const int blk = blockIdx.x % NPASSBLK;
  const int tid = threadIdx.x;
  const int* rows = (m == 0) ? r0 : (m == 1) ? r1 : r2;
  const int* cols = (m == 0) ? c0 : (m == 1) ? c1 : c2;
  const float* vals = (m == 0) ? v0 : (m == 1) ? v1 : v2;
  const int nnz  = (m == 0) ? nnz0 : (m == 1) ? nnz1 : nnz2;
  const int nbuk = (m == 0) ? nb0 : (m == 1) ? nb1 : nb2;
  const int bukbase = (m == 0) ? 0 : (m == 1) ? nb0 : nb0 + nb1;
  const int chunk = (nnz + NPASSBLK - 1) / NPASSBLK;
  for (int b = tid; b < nbuk; b += BT)
    lcur[b] = S[(size_t)(bukbase + b) * NPASSBLK + blk];
  __syncthreads();
  const int i0 = blk * chunk;
  const int i1 = min(i0 + chunk, nnz);
  for (int i = i0 + tid; i < i1; i += BT) {
    const int r = rows[i];
    const int p = atomicAdd(&lcur[r >> RB_SHIFT], 1);
    prT[p] = make_int2(cols[i] | ((r & (RB - 1)) << 26), __float_as_int(vals[i]));
  }
}

__global__ __launch_bounds__(256)
void bucket_to_csr3(const int* __restrict__ S, const int2* __restrict__ prT,
                    int2* __restrict__ pA, int* __restrict__ ptA,
                    int2* __restrict__ pE, int* __restrict__ ptE,
                    int2* __restrict__ pI, int* __restrict__ ptI,
                    int nr0, int nr1, int nr2,
                    int nb0, int nb1, int nnz0, int nnz1) {
  __shared__ int h[RB + 1];
  __shared__ int cur[RB];
  const int b = blockIdx.x, tid = threadIdx.x;
  const int m = (b < nb0) ? 0 : (b < nb0 + nb1) ? 1 : 2;
  const int lb = (m == 0) ? b : (m == 1) ? b - nb0 : b - nb0 - nb1;
  const int nnzbase = (m == 0) ? 0 : (m == 1) ? nnz0 : nnz0 + nnz1;
  const int n_rows = (m == 0) ? nr0 : (m == 1) ? nr1 : nr2;
  int2* pr = (m == 0) ? pA : (m == 1) ? pE : pI;
  int* ptr = (m == 0) ? ptA : (m == 1) ? ptE : ptI;

  const int js = S[(size_t)b * NPASSBLK];
  const int je = S[(size_t)(b + 1) * NPASSBLK];
  if (tid <= RB) h[tid] = 0;
  __syncthreads();
  for (int j = js + tid; j < je; j += 256)
    atomicAdd(&h[((unsigned)prT[j].x) >> 26], 1);
  __syncthreads();
  if (tid == 0) {
    int run = js;
    for (int t = 0; t < RB; ++t) { int c = h[t]; h[t] = run; cur[t] = run; run += c; }
    h[RB] = run;   // == je
  }
  __syncthreads();
  if (tid <= RB) {
    const int r = lb * RB + tid;
    if (r <= n_rows) ptr[r] = h[tid] - nnzbase;
  }
  for (int j = js + tid; j < je; j += 256) {
    const int2 e = prT[j];
    const unsigned cw = (unsigned)e.x;
    const int p = atomicAdd(&cur[cw >> 26], 1);
    pr[p - nnzbase] = make_int2((int)(cw & 0x03FFFFFFu), e.y);
  }
}

// ----------------------------- CSR SpMM (quad-gather) ----------------------
template <int UNR>
__device__ __forceinline__ void seg_accum(const int* __restrict__ ptr,
                                          const int2* __restrict__ pr,
                                          const unsigned* __restrict__ Xq,
                                          int wid, int g, f32x2* acc) {
  int j = ptr[wid];
  const int je = ptr[wid + 1];
  for (; j < je; j += 4 * UNR) {
    int2 p[UNR];
#pragma unroll
    for (int u = 0; u < UNR; ++u) {
      const int jj = j + 4 * u + g;
      p[u] = (jj < je) ? pr[jj] : make_int2(0, 0);
    }
    uint4 d[UNR];
#pragma unroll
    for (int u = 0; u < UNR; ++u)
      d[u] = *(const uint4*)(Xq + (size_t)p[u].x * 64);
#pragma unroll
    for (int u = 0; u < UNR; ++u) {
      const float v = __int_as_float(p[u].y);
      const f32x2 vv = {v, v};
      acc[0] = __builtin_elementwise_fma(vv, bf2v(d[u].x), acc[0]);
      acc[1] = __builtin_elementwise_fma(vv, bf2v(d[u].y), acc[1]);
      acc[2] = __builtin_elementwise_fma(vv, bf2v(d[u].z), acc[2]);
      acc[3] = __builtin_elementwise_fma(vv, bf2v(d[u].w), acc[3]);
    }
  }
}

template <bool SIG, int UNR>
__device__ __forceinline__ void spmm_body(const int* __restrict__ ptr,
                                          const int2* __restrict__ pr,
                                          const unsigned* __restrict__ X,
                                          unsigned* __restrict__ Y,
                                          int n_rows, int blk) {
  const int wid = (blk << 2) + (threadIdx.x >> 6);
  if (wid >= n_rows) return;
  const int lane = threadIdx.x & 63;
  const int g = lane >> 4;
  const int q = lane & 15;
  f32x2 acc[4];
#pragma unroll
  for (int k = 0; k < 4; ++k) acc[k] = (f32x2){0.f, 0.f};
  seg_accum<UNR>(ptr, pr, X + q * 4, wid, g, acc);
#pragma unroll
  for (int k = 0; k < 4; ++k) {
    acc[k].x += __shfl_xor(acc[k].x, 16);
    acc[k].y += __shfl_xor(acc[k].y, 16);
    acc[k].x += __shfl_xor(acc[k].x, 32);
    acc[k].y += __shfl_xor(acc[k].y, 32);
  }
  if (g == 0) {
    if (SIG) {
#pragma unroll
      for (int k = 0; k < 4; ++k) {
        acc[k].x = 1.f / (1.f + __expf(-acc[k].x));
        acc[k].y = 1.f / (1.f + __expf(-acc[k].y));
      }
    }
    uint4 o;
    o.x = (unsigned)bf16rne(acc[0].x) | ((unsigned)bf16rne(acc[0].y) << 16);
    o.y = (unsigned)bf16rne(acc[1].x) | ((unsigned)bf16rne(acc[1].y) << 16);
    o.z = (unsigned)bf16rne(acc[2].x) | ((unsigned)bf16rne(acc[2].y) << 16);
    o.w = (unsigned)bf16rne(acc[3].x) | ((unsigned)bf16rne(acc[3].y) << 16);
    *(uint4*)(Y + (size_t)wid * 64 + q * 4) = o;
  }
}

// fused level-1 SpMMs: blocks [0,split) adj->n1 (UNR4), rest incT->e1 (UNR1)
__global__ __launch_bounds__(256)
void csr_spmm_l1(const int* __restrict__ ptrA, const int2* __restrict__ prA,
                 const unsigned* __restrict__ XA, unsigned* __restrict__ YA, int nA,
                 const int* __restrict__ ptrE, const int2* __restrict__ prE,
                 const unsigned* __restrict__ XE, unsigned* __restrict__ YE, int nE,
                 int split) {
  if ((int)blockIdx.x < split)
    spmm_body<true, 4>(ptrA, prA, XA, YA, nA, blockIdx.x);
  else
    spmm_body<true, 1>(ptrE, prE, XE, YE, nE, blockIdx.x - split);
}

// Fused level-2 merge: out[r] = sigmoid( adj-seg(XA) + inc-seg(XB) ), f32 out.
__global__ __launch_bounds__(256)
void csr_spmm2_sig(const int* __restrict__ ptrA, const int2* __restrict__ prA,
                   const unsigned* __restrict__ XA,
                   const int* __restrict__ ptrB, const int2* __restrict__ prB,
                   const unsigned* __restrict__ XB,
                   float* __restrict__ Y, int n_rows) {
  const int wid = (blockIdx.x << 2) + (threadIdx.x >> 6);
  if (wid >= n_rows) return;
  const int lane = threadIdx.x & 63;
  const int g = lane >> 4;
  const int q = lane & 15;
  f32x2 acc[4];
#pragma unroll
  for (int k = 0; k < 4; ++k) acc[k] = (f32x2){0.f, 0.f};
  seg_accum<4>(ptrA, prA, XA + q * 4, wid, g, acc);
  seg_accum<1>(ptrB, prB, XB + q * 4, wid, g, acc);
#pragma unroll
  for (int k = 0; k < 4; ++k) {
    acc[k].x += __shfl_xor(acc[k].x, 16);
    acc[k].y += __shfl_xor(acc[k].y, 16);
    acc[k].x += __shfl_xor(acc[k].x, 32);
    acc[k].y += __shfl_xor(acc[k].y, 32);
  }
  if (g == 0) {
#pragma unroll
    for (int k = 0; k < 4; ++k) {
      acc[k].x = 1.f / (1.f + __expf(-acc[k].x));
      acc[k].y = 1.f / (1.f + __expf(-acc[k].y));
    }
    float4* yp = (float4*)(Y + (size_t)wid * CF + q * 8);
    yp[0] = make_float4(acc[0].x, acc[0].y, acc[1].x, acc[1].y);
    yp[1] = make_float4(acc[2].x, acc[2].y, acc[3].x, acc[3].y);
  }
}

// ---------------------------------------------------------------------------
extern "C" void kernel_launch(void* const* d_in, const int* in_sizes, int n_in,
                              void* d_out, int out_size, void* d_ws, size_t ws_size,
                              hipStream_t stream) {
  const float* x      = (const float*)d_in[0];
  const float* W1_00  = (const float*)d_in[1];
  const float* W1_01  = (const float*)d_in[2];
  const float* W2_00  = (const float*)d_in[3];
  const float* W2_10  = (const float*)d_in[4];
  const int*   adj_rows = (const int*)d_in[5];
  const int*   adj_cols = (const int*)d_in[6];
  const float* adj_vals = (const float*)d_in[7];
  const int*   inc_rows = (const int*)d_in[8];
  const int*   inc_cols = (const int*)d_in[9];
  const float* inc_vals = (const float*)d_in[10];

  const int adj_nnz = in_sizes[5];       // 3,200,000
  const int inc_nnz = in_sizes[8];       // 400,000
  const int NN = in_sizes[0] / CF;       // 100,000 nodes
  const int EN = 200000;                 // edges (problem constant)

  const long long NE = (long long)NN * CF;   // node features
  const long long EE = (long long)EN * CF;   // edge features
  const int PN = ((NN + 2) & ~1);            // padded (8B-align int2 arrays)
  const int PE = ((EN + 2) & ~1);

  // ---- workspace layout ----
  unsigned short* tA = (unsigned short*)d_ws;   // NE bf16 ; prT alias at build
  unsigned short* n1 = tA + NE;                 // NE bf16 ; prT spill region
  unsigned short* e1 = n1 + NE;                 // EE bf16 ; cnt/S alias at build
  int*   ptr_a = (int*)(e1 + EE);
  int*   cur_a = ptr_a + PN;                    // (unused, layout stability)
  int2*  pr_a  = (int2*)(cur_a + PN);
  int*   ptr_e = (int*)(pr_a + adj_nnz);
  int*   cur_e = ptr_e + PE;                    // (unused)
  int2*  pr_e  = (int2*)(cur_e + PE);
  int*   ptr_i = (int*)(pr_e + inc_nnz);
  int*   cur_i = ptr_i + PN;                    // (unused)
  int2*  pr_i  = (int2*)(cur_i + PN);
  int*   blks  = (int*)(pr_i + inc_nnz);        // 2048 ints
  short* wp = (short*)(((uintptr_t)(blks + 2048) + 63) & ~(uintptr_t)63);
  short* w00 = wp;             // hi at +0, lo at +16384
  short* w01 = wp + 2 * 16384;
  short* w20 = wp + 4 * 16384;
  short* w21 = wp + 6 * 16384;

  // build-time scratch aliased onto feature buffers (dead until GEMMs/SpMMs):
  // prT: total nnz 4M x 8 B = 32 MB  (tA+n1 region = 51.2 MB)
  // cnt/S: nS = totbuk*256+1 = 1,600,257 ints each (6.4 MB x2; e1 = 51.2 MB)
  int2* prT  = (int2*)tA;
  int*  cntA = (int*)e1;
  int*  SA   = cntA + 1600512;

  unsigned short* t1 = (unsigned short*)d_out;  // bf16 scratch; dead before final write
  float* outf = (float*)d_out;

  const dim3 blk(256);
  const int gN = (NN + 63) / 64;                // 1563
  const int gE = (EN + 63) / 64;                // 3125
  const int nbukN = (NN + RB - 1) >> RB_SHIFT;  // 1563
  const int nbukE = (EN + RB - 1) >> RB_SHIFT;  // 3125
  const int totbuk = nbukN + nbukE + nbukN;     // 6251
  const int nS = totbuk * NPASSBLK + 1;         // 1,600,257
  const int nbS = (nS + 1023) / 1024;           // 1563 (<= 2048 scan_sums cap)
  const int ldsbk = nbukE * 4;                  // max bucket count LDS bytes

  // ---- pack weights (1) ----
  pack_w4<<<32, blk, 0, stream>>>(W1_00, W1_01, W2_00, W2_10, wp);

  // ---- fused CSR builds (2-7): count3, scan x3, scatter3, to_csr3 ----
  // matrix 0: adj by adj_rows; 1: B1^T by inc_cols (rows=edges); 2: B1 by inc_rows
  bucket_count3<<<3 * NPASSBLK, dim3(BT), ldsbk, stream>>>(
      adj_rows, inc_cols, inc_rows, cntA,
      adj_nnz, inc_nnz, inc_nnz, nbukN, nbukE, nbukN);
  scan_block<<<nbS, blk, 0, stream>>>(cntA, SA, blks, nS);
  scan_sums<<<1, blk, 0, stream>>>(blks, nbS);
  scan_add<<<nbS, blk, 0, stream>>>(SA, blks, nS);
  bucket_scatter3<<<3 * NPASSBLK, dim3(BT), ldsbk, stream>>>(
      adj_rows, adj_cols, adj_vals,
      inc_cols, inc_rows, inc_vals,
      inc_rows, inc_cols, inc_vals,
      SA, prT, adj_nnz, inc_nnz, inc_nnz, nbukN, nbukE, nbukN);
  bucket_to_csr3<<<totbuk, blk, 0, stream>>>(
      SA, prT, pr_a, ptr_a, pr_e, ptr_e, pr_i, ptr_i,
      NN, EN, NN, nbukN, nbukE, adj_nnz, inc_nnz);

  // ---- level 1 GEMMs fused (8): t1 = x@W1_00, tA = x@W1_01 ----
  gemm_f32_l1<<<2 * gN, dim3(128), 0, stream>>>(x, w00, w01, t1, tA, NN, gN);

  // ---- level 1 SpMMs fused (9): n1 = sig(adj-seg t1), e1 = sig(incT-seg tA) --
  const int spN = (NN + 3) / 4, spE = (EN + 3) / 4;
  csr_spmm_l1<<<spN + spE, blk, 0, stream>>>(
      ptr_a, pr_a, (const unsigned*)t1, (unsigned*)n1, NN,
      ptr_e, pr_e, (const unsigned*)tA, (unsigned*)e1, EN, spN);

  // ---- level 2 GEMMs fused (10): n1 = n1@W2_00, e1 = e1@W2_10 (in-place) ----
  gemm_b16_l2<<<gN + gE, dim3(128), 0, stream>>>(
      (unsigned short*)n1, w20, (unsigned short*)e1, w21, NN, EN, gN);

  // ---- fused level-2 SpMMs + merge sigmoid (11) ----
  csr_spmm2_sig<<<spN, blk, 0, stream>>>(ptr_a, pr_a, (const unsigned*)n1,
                                         ptr_i, pr_i, (const unsigned*)e1, outf, NN);
}